// Round 1
// baseline (250.913 us; speedup 1.0000x reference)
//
#include <hip/hip_runtime.h>
#include <math.h>

typedef __bf16 bf16_t;
typedef bf16_t bf16x8 __attribute__((ext_vector_type(8)));
typedef bf16_t bf16x4 __attribute__((ext_vector_type(4)));
typedef short  s16x4  __attribute__((ext_vector_type(4)));
typedef float  f32x4  __attribute__((ext_vector_type(4)));

#define DIM_   1024
#define NHEADS 16
#define HDIM   64
#define SEQ    2048
#define BATCH  2

// log2(e)/8 : folded into q at RoPE time so attention softmax is exp2(s)
#define QK_SCALE 0.18033688011112042f

__device__ __forceinline__ s16x4 as_s16x4(bf16x4 v) {
    union { bf16x4 b; s16x4 s; } u; u.b = v; return u.s;
}

// async global->LDS, 16 B per lane; LDS dest = wave-uniform base + lane*16
__device__ __forceinline__ void gld16(const bf16_t* g, bf16_t* l) {
    __builtin_amdgcn_global_load_lds(
        (const __attribute__((address_space(1))) void*)g,
        (__attribute__((address_space(3))) void*)l, 16, 0, 0);
}

// ---------------------------------------------------------------------------
// Fused fp32->bf16 cast of x, w_qkv, w_out.
// ---------------------------------------------------------------------------
#define XCNT   (4096u * 1024u)
#define WQCNT  (3072u * 1024u)
#define WOCNT  (1024u * 1024u)
__global__ __launch_bounds__(256) void cast3(const float* __restrict__ s0,
                                             const float* __restrict__ s1,
                                             const float* __restrict__ s2,
                                             bf16_t* __restrict__ d0,
                                             bf16_t* __restrict__ d1,
                                             bf16_t* __restrict__ d2) {
    size_t i = ((size_t)blockIdx.x * 256 + threadIdx.x) * 8;
    const float* s; bf16_t* d; size_t off;
    if (i < XCNT)               { s = s0; d = d0; off = i; }
    else if (i < XCNT + WQCNT)  { s = s1; d = d1; off = i - XCNT; }
    else                        { s = s2; d = d2; off = i - XCNT - WQCNT; }
    float4 a = *(const float4*)(s + off);
    float4 b = *(const float4*)(s + off + 4);
    bf16x8 o = { (bf16_t)a.x, (bf16_t)a.y, (bf16_t)a.z, (bf16_t)a.w,
                 (bf16_t)b.x, (bf16_t)b.y, (bf16_t)b.z, (bf16_t)b.w };
    *(bf16x8*)(d + off) = o;
}

// ---------------------------------------------------------------------------
// m97-style bf16 GEMM (unchanged): 128x128 tile, BK=32, global_load_lds
// width-16 staging, unpadded LDS, b128 frag reads.
// ---------------------------------------------------------------------------
template <bool QKV>
__global__ __launch_bounds__(256) void gemm_lds(const bf16_t* __restrict__ A,
                                                const bf16_t* __restrict__ B,
                                                const float* __restrict__ bias,
                                                void* __restrict__ Cout,
                                                bf16_t* __restrict__ vt,
                                                int M, int N, int K) {
    __shared__ __align__(16) bf16_t As[128 * 32];
    __shared__ __align__(16) bf16_t Bs[128 * 32];
    const int tid  = threadIdx.x;
    const int m0   = blockIdx.y * 128;
    const int n0   = blockIdx.x * 128;
    const int w    = tid >> 6;
    const int lane = tid & 63;
    const int m16  = lane & 15;
    const int quad = lane >> 4;
    const int wm   = (w >> 1) * 64;
    const int wn   = (w & 1) * 64;
    const int lrow = lane >> 2;
    const int lcol = (lane & 3) * 8;

    const bf16_t* pa0 = A + (size_t)(m0 + w * 16 + lrow) * K + lcol;
    const bf16_t* pb0 = B + (size_t)(n0 + w * 16 + lrow) * K + lcol;
    bf16_t* lA0 = &As[(w * 16) * 32];
    bf16_t* lA1 = &As[(64 + w * 16) * 32];
    bf16_t* lB0 = &Bs[(w * 16) * 32];
    bf16_t* lB1 = &Bs[(64 + w * 16) * 32];

    f32x4 acc[4][4] = {};

    for (int k0 = 0; k0 < K; k0 += 32) {
        __syncthreads();
        gld16(pa0 + k0, lA0);
        gld16(pa0 + (size_t)64 * K + k0, lA1);
        gld16(pb0 + k0, lB0);
        gld16(pb0 + (size_t)64 * K + k0, lB1);
        __syncthreads();

        bf16x8 af[4], bfr[4];
#pragma unroll
        for (int i = 0; i < 4; ++i)
            af[i] = *(const bf16x8*)(&As[(wm + i * 16 + m16) * 32 + quad * 8]);
#pragma unroll
        for (int j = 0; j < 4; ++j)
            bfr[j] = *(const bf16x8*)(&Bs[(wn + j * 16 + m16) * 32 + quad * 8]);
#pragma unroll
        for (int i = 0; i < 4; ++i)
#pragma unroll
            for (int j = 0; j < 4; ++j)
                acc[i][j] = __builtin_amdgcn_mfma_f32_16x16x32_bf16(af[i], bfr[j], acc[i][j], 0, 0, 0);
    }

    if (QKV && n0 >= 2 * DIM_) {
        const int b      = m0 >> 11;
        const int s_base = (m0 & (SEQ - 1)) + wm;
#pragma unroll
        for (int j = 0; j < 4; ++j) {
            const int cit = wn + j * 16 + m16;
            const int h   = ((n0 - 2 * DIM_) >> 6) + (cit >> 6);
            const int d   = cit & 63;
            bf16_t* vrow = vt + ((size_t)(b * 16 + h) * 64 + d) * SEQ + s_base;
#pragma unroll
            for (int i = 0; i < 4; ++i) {
                bf16x4 ov = { (bf16_t)acc[i][j][0], (bf16_t)acc[i][j][1],
                              (bf16_t)acc[i][j][2], (bf16_t)acc[i][j][3] };
                *(bf16x4*)(vrow + i * 16 + quad * 4) = ov;
            }
        }
    } else if (QKV) {
        bf16_t* C = (bf16_t*)Cout;
#pragma unroll
        for (int i = 0; i < 4; ++i)
#pragma unroll
            for (int j = 0; j < 4; ++j) {
                const int col = n0 + wn + j * 16 + m16;
#pragma unroll
                for (int r = 0; r < 4; ++r)
                    C[(size_t)(m0 + wm + i * 16 + quad * 4 + r) * N + col] = (bf16_t)acc[i][j][r];
            }
    } else {
        float* C = (float*)Cout;
#pragma unroll
        for (int j = 0; j < 4; ++j) {
            const int col = n0 + wn + j * 16 + m16;
            const float bv = bias[col];
#pragma unroll
            for (int i = 0; i < 4; ++i)
#pragma unroll
                for (int r = 0; r < 4; ++r)
                    C[(size_t)(m0 + wm + i * 16 + quad * 4 + r) * N + col] = acc[i][j][r] + bv;
        }
    }
}

// ---------------------------------------------------------------------------
// RoPE in place on bf16 qkv (q and k thirds). q scaled by QK_SCALE.
// ---------------------------------------------------------------------------
__global__ __launch_bounds__(256) void rope_bf16(bf16_t* __restrict__ qkv) {
    __shared__ float ctab[8][32];
    __shared__ float stab[8][32];
    const int tid = threadIdx.x;
    const int sl  = tid >> 5, j = tid & 31;
    const int s   = (int)((blockIdx.x * 8 + sl) & (SEQ - 1));
    const float freq = exp2f(-0.41524101186092029f * (float)j);  // 10000^(-j/32)
    float sn, cs;
    sincosf((float)s * freq, &sn, &cs);
    ctab[sl][j] = cs;
    stab[sl][j] = sn;
    __syncthreads();

    const int gid   = blockIdx.x * 256 + tid;
    const int m     = gid >> 5;
    const int rr    = gid & 31;
    const int which = rr >> 4;
    const int hh    = rr & 15;
    const float osc = (which == 0) ? QK_SCALE : 1.0f;

    bf16_t* p = qkv + (size_t)m * (3 * DIM_) + which * DIM_ + hh * HDIM;
    union { bf16_t e[64]; bf16x8 v[8]; } X, O;
#pragma unroll
    for (int i = 0; i < 8; ++i) X.v[i] = *(const bf16x8*)(p + i * 8);
#pragma unroll
    for (int t = 0; t < 32; ++t) {
        const float x1 = (float)X.e[2 * t];
        const float x2 = (float)X.e[2 * t + 1];
        const float c  = ctab[sl][t];
        const float s2 = stab[sl][t];
        O.e[t]      = (bf16_t)((x1 * c - x2 * s2) * osc);
        O.e[32 + t] = (bf16_t)((x1 * s2 + x2 * c) * osc);
    }
#pragma unroll
    for (int i = 0; i < 8; ++i) *(bf16x8*)(p + i * 8) = O.v[i];
}

// ---------------------------------------------------------------------------
// Flash attention, key-split waves. NO K/V LDS staging: each wave's K rows
// (w*16+m16) and V^T columns (w*16+quad*4) are wave-private (zero cross-wave
// sharing), and K/V per head = 256 KB each = L2-resident. Fragments load
// DIRECTLY from global with pointer-increment addressing; no barriers in the
// main loop, so waves drift and TLP (16 waves/CU) hides the L2 latency.
// LDS is used only for the epilogue l/O reductions.
// ---------------------------------------------------------------------------
__global__ __launch_bounds__(256) void attn_mfma(const bf16_t* __restrict__ qkv,
                                                 const bf16_t* __restrict__ vt,
                                                 bf16_t* __restrict__ out) {
    __shared__ __align__(16) char smem[17664];
    float* Ored = (float*)smem;              // 16640 B
    float* Lred = (float*)(smem + 16640);    // 1024 B

    const int tid  = threadIdx.x;
    const int w    = tid >> 6;
    const int lane = tid & 63;
    const int m16  = lane & 15;
    const int quad = lane >> 4;
    const int bh   = blockIdx.y;
    const int b    = bh >> 4;
    const int hh   = bh & 15;
    const int q0   = blockIdx.x * 64;

    const size_t rs = 3 * DIM_;
    const bf16_t* qbase = qkv + (size_t)(b * SEQ) * rs + hh * HDIM;
    const bf16_t* kbase = qbase + DIM_;
    const bf16_t* vtg   = vt + (size_t)bh * 64 * SEQ;

    // Q fragments: qf[n][kt] = Q[q0+n*16+m16][kt*32+quad*8 ..+7]
    bf16x8 qf[4][2];
#pragma unroll
    for (int n = 0; n < 4; ++n)
#pragma unroll
        for (int kt = 0; kt < 2; ++kt)
            qf[n][kt] = *(const bf16x8*)(qbase + (size_t)(q0 + n * 16 + m16) * rs + kt * 32 + quad * 8);

    f32x4 o[4][4] = {};  // o[ds][n]: partial O^T over this wave's keys
    float lp[4] = {};    // per-lane partial l for q = n*16+m16

    // direct-fragment global pointers (advance by one tile per iteration)
    const bf16_t* kp = kbase + (size_t)(w * 16 + m16) * rs + quad * 8;
    const bf16_t* vp = vtg + (size_t)m16 * SEQ + w * 16 + quad * 4;

    for (int t = 0; t < 32; ++t) {
        // K fragment for this wave's 16 keys: rows t*64+w*16+m16, cols quad*8
        bf16x8 ak0 = *(const bf16x8*)(kp);
        bf16x8 ak1 = *(const bf16x8*)(kp + 32);
        // V^T fragments: rows ds*16+m16 (= dim), cols t*64+w*16+quad*4 (= key)
        bf16x4 va[4];
#pragma unroll
        for (int ds = 0; ds < 4; ++ds)
            va[ds] = *(const bf16x4*)(vp + (size_t)ds * 16 * SEQ);

        s16x4 pb[4];
#pragma unroll
        for (int n = 0; n < 4; ++n) {
            f32x4 c = {};
            c = __builtin_amdgcn_mfma_f32_16x16x32_bf16(ak0, qf[n][0], c, 0, 0, 0);
            c = __builtin_amdgcn_mfma_f32_16x16x32_bf16(ak1, qf[n][1], c, 0, 0, 0);
            bf16x4 pv;
#pragma unroll
            for (int r = 0; r < 4; ++r) {
                const float p = __builtin_amdgcn_exp2f(c[r]);
                lp[n] += p;
                pv[r] = (bf16_t)p;
            }
            pb[n] = as_s16x4(pv);
        }

        __builtin_amdgcn_s_setprio(1);
#pragma unroll
        for (int ds = 0; ds < 4; ++ds)
#pragma unroll
            for (int n = 0; n < 4; ++n)
                o[ds][n] = __builtin_amdgcn_mfma_f32_16x16x16bf16_1k(as_s16x4(va[ds]), pb[n], o[ds][n], 0, 0, 0);
        __builtin_amdgcn_s_setprio(0);

        kp += (size_t)64 * rs;
        vp += 64;
    }

    // ---- l reduction: over quads (shfl), then over waves (LDS) ----
#pragma unroll
    for (int n = 0; n < 4; ++n) {
        lp[n] += __shfl_xor(lp[n], 16);
        lp[n] += __shfl_xor(lp[n], 32);
    }
    if (quad == 0) {
#pragma unroll
        for (int n = 0; n < 4; ++n) Lred[w * 64 + n * 16 + m16] = lp[n];
    }
    __syncthreads();
    const float linv = 1.0f / (Lred[lane] + Lred[64 + lane] + Lred[128 + lane] + Lred[192 + lane]);

    // ---- O reduction: 4 phases; wave p owns dim-quarter p ----
    const size_t obase = (size_t)(b * SEQ + q0 + lane) * DIM_ + hh * HDIM;
#pragma unroll
    for (int p = 0; p < 4; ++p) {
        __syncthreads();
#pragma unroll
        for (int n = 0; n < 4; ++n)
#pragma unroll
            for (int r = 0; r < 4; ++r)
                Ored[w * 1040 + (quad * 4 + r) * 65 + n * 16 + m16] = o[p][n][r];
        __syncthreads();
        if (w == p) {
            union { bf16_t e[16]; bf16x8 v[2]; } ob;
#pragma unroll
            for (int d = 0; d < 16; ++d) {
                const float v = Ored[d * 65 + lane] + Ored[1040 + d * 65 + lane] +
                                Ored[2080 + d * 65 + lane] + Ored[3120 + d * 65 + lane];
                ob.e[d] = (bf16_t)(v * linv);
            }
            *(bf16x8*)(out + obase + p * 16)     = ob.v[0];
            *(bf16x8*)(out + obase + p * 16 + 8) = ob.v[1];
        }
    }
}

// ---------------------------------------------------------------------------
extern "C" void kernel_launch(void* const* d_in, const int* in_sizes, int n_in,
                              void* d_out, int out_size, void* d_ws, size_t ws_size,
                              hipStream_t stream) {
    const float* x     = (const float*)d_in[0];
    const float* w_qkv = (const float*)d_in[1];
    const float* w_out = (const float*)d_in[2];
    const float* b_out = (const float*)d_in[3];
    float* out = (float*)d_out;

    const int M = BATCH * SEQ;  // 4096

    bf16_t* qkv_b  = (bf16_t*)d_ws;                            // 4096x3072
    bf16_t* attn_b = qkv_b + (size_t)M * 3 * DIM_;             // 4096x1024
    bf16_t* vt_b   = attn_b + (size_t)M * DIM_;                // 32 heads x 64 x SEQ
    bf16_t* xb     = vt_b + (size_t)BATCH * NHEADS * HDIM * SEQ;
    bf16_t* wqkvb  = xb + (size_t)M * DIM_;
    bf16_t* woutb  = wqkvb + (size_t)3 * DIM_ * DIM_;

    // 0) cast x, w_qkv, w_out to bf16
    cast3<<<(XCNT + WQCNT + WOCNT) / (256 * 8), 256, 0, stream>>>(
        x, w_qkv, w_out, xb, wqkvb, woutb);

    // 1) qkv = x @ w_qkv^T  (q,k -> qkv_b; v -> vt_b transposed)
    gemm_lds<true><<<dim3(3 * DIM_ / 128, M / 128), 256, 0, stream>>>(
        xb, wqkvb, nullptr, qkv_b, vt_b, M, 3 * DIM_, DIM_);

    // 2) RoPE in place on q,k
    rope_bf16<<<(M * 2 * NHEADS) / 256, 256, 0, stream>>>(qkv_b);

    // 3) flash attention -> attn_b
    attn_mfma<<<dim3(SEQ / 64, BATCH * NHEADS), 256, 0, stream>>>(qkv_b, vt_b, attn_b);

    // 4) out = attn @ w_out^T + b_out (fp32)
    gemm_lds<false><<<dim3(DIM_ / 128, M / 128), 256, 0, stream>>>(
        attn_b, woutb, b_out, out, nullptr, M, DIM_, DIM_);
}

// Round 2
// 249.778 us; speedup vs baseline: 1.0045x; 1.0045x over previous
//
#include <hip/hip_runtime.h>
#include <math.h>

typedef __bf16 bf16_t;
typedef bf16_t bf16x8 __attribute__((ext_vector_type(8)));
typedef bf16_t bf16x4 __attribute__((ext_vector_type(4)));
typedef short  s16x4  __attribute__((ext_vector_type(4)));
typedef float  f32x4  __attribute__((ext_vector_type(4)));

#define DIM_   1024
#define NHEADS 16
#define HDIM   64
#define SEQ    2048
#define BATCH  2

// log2(e)/8 : folded into q at RoPE time so attention softmax is exp2(s)
#define QK_SCALE 0.18033688011112042f

__device__ __forceinline__ s16x4 as_s16x4(bf16x4 v) {
    union { bf16x4 b; s16x4 s; } u; u.b = v; return u.s;
}

// async global->LDS, 16 B per lane; LDS dest = wave-uniform base + lane*16
__device__ __forceinline__ void gld16(const bf16_t* g, bf16_t* l) {
    __builtin_amdgcn_global_load_lds(
        (const __attribute__((address_space(1))) void*)g,
        (__attribute__((address_space(3))) void*)l, 16, 0, 0);
}

// ---------------------------------------------------------------------------
// Fused fp32->bf16 cast of x, w_qkv, w_out.
// ---------------------------------------------------------------------------
#define XCNT   (4096u * 1024u)
#define WQCNT  (3072u * 1024u)
#define WOCNT  (1024u * 1024u)
__global__ __launch_bounds__(256) void cast3(const float* __restrict__ s0,
                                             const float* __restrict__ s1,
                                             const float* __restrict__ s2,
                                             bf16_t* __restrict__ d0,
                                             bf16_t* __restrict__ d1,
                                             bf16_t* __restrict__ d2) {
    size_t i = ((size_t)blockIdx.x * 256 + threadIdx.x) * 8;
    const float* s; bf16_t* d; size_t off;
    if (i < XCNT)               { s = s0; d = d0; off = i; }
    else if (i < XCNT + WQCNT)  { s = s1; d = d1; off = i - XCNT; }
    else                        { s = s2; d = d2; off = i - XCNT - WQCNT; }
    float4 a = *(const float4*)(s + off);
    float4 b = *(const float4*)(s + off + 4);
    bf16x8 o = { (bf16_t)a.x, (bf16_t)a.y, (bf16_t)a.z, (bf16_t)a.w,
                 (bf16_t)b.x, (bf16_t)b.y, (bf16_t)b.z, (bf16_t)b.w };
    *(bf16x8*)(d + off) = o;
}

// ---------------------------------------------------------------------------
// m97-style bf16 GEMM (unchanged): 128x128 tile, BK=32, global_load_lds
// width-16 staging, unpadded LDS, b128 frag reads.
// ---------------------------------------------------------------------------
template <bool QKV>
__global__ __launch_bounds__(256) void gemm_lds(const bf16_t* __restrict__ A,
                                                const bf16_t* __restrict__ B,
                                                const float* __restrict__ bias,
                                                void* __restrict__ Cout,
                                                bf16_t* __restrict__ vt,
                                                int M, int N, int K) {
    __shared__ __align__(16) bf16_t As[128 * 32];
    __shared__ __align__(16) bf16_t Bs[128 * 32];
    const int tid  = threadIdx.x;
    const int m0   = blockIdx.y * 128;
    const int n0   = blockIdx.x * 128;
    const int w    = tid >> 6;
    const int lane = tid & 63;
    const int m16  = lane & 15;
    const int quad = lane >> 4;
    const int wm   = (w >> 1) * 64;
    const int wn   = (w & 1) * 64;
    const int lrow = lane >> 2;
    const int lcol = (lane & 3) * 8;

    const bf16_t* pa0 = A + (size_t)(m0 + w * 16 + lrow) * K + lcol;
    const bf16_t* pb0 = B + (size_t)(n0 + w * 16 + lrow) * K + lcol;
    bf16_t* lA0 = &As[(w * 16) * 32];
    bf16_t* lA1 = &As[(64 + w * 16) * 32];
    bf16_t* lB0 = &Bs[(w * 16) * 32];
    bf16_t* lB1 = &Bs[(64 + w * 16) * 32];

    f32x4 acc[4][4] = {};

    for (int k0 = 0; k0 < K; k0 += 32) {
        __syncthreads();
        gld16(pa0 + k0, lA0);
        gld16(pa0 + (size_t)64 * K + k0, lA1);
        gld16(pb0 + k0, lB0);
        gld16(pb0 + (size_t)64 * K + k0, lB1);
        __syncthreads();

        bf16x8 af[4], bfr[4];
#pragma unroll
        for (int i = 0; i < 4; ++i)
            af[i] = *(const bf16x8*)(&As[(wm + i * 16 + m16) * 32 + quad * 8]);
#pragma unroll
        for (int j = 0; j < 4; ++j)
            bfr[j] = *(const bf16x8*)(&Bs[(wn + j * 16 + m16) * 32 + quad * 8]);
#pragma unroll
        for (int i = 0; i < 4; ++i)
#pragma unroll
            for (int j = 0; j < 4; ++j)
                acc[i][j] = __builtin_amdgcn_mfma_f32_16x16x32_bf16(af[i], bfr[j], acc[i][j], 0, 0, 0);
    }

    if (QKV && n0 >= 2 * DIM_) {
        const int b      = m0 >> 11;
        const int s_base = (m0 & (SEQ - 1)) + wm;
#pragma unroll
        for (int j = 0; j < 4; ++j) {
            const int cit = wn + j * 16 + m16;
            const int h   = ((n0 - 2 * DIM_) >> 6) + (cit >> 6);
            const int d   = cit & 63;
            bf16_t* vrow = vt + ((size_t)(b * 16 + h) * 64 + d) * SEQ + s_base;
#pragma unroll
            for (int i = 0; i < 4; ++i) {
                bf16x4 ov = { (bf16_t)acc[i][j][0], (bf16_t)acc[i][j][1],
                              (bf16_t)acc[i][j][2], (bf16_t)acc[i][j][3] };
                *(bf16x4*)(vrow + i * 16 + quad * 4) = ov;
            }
        }
    } else if (QKV) {
        bf16_t* C = (bf16_t*)Cout;
#pragma unroll
        for (int i = 0; i < 4; ++i)
#pragma unroll
            for (int j = 0; j < 4; ++j) {
                const int col = n0 + wn + j * 16 + m16;
#pragma unroll
                for (int r = 0; r < 4; ++r)
                    C[(size_t)(m0 + wm + i * 16 + quad * 4 + r) * N + col] = (bf16_t)acc[i][j][r];
            }
    } else {
        float* C = (float*)Cout;
#pragma unroll
        for (int j = 0; j < 4; ++j) {
            const int col = n0 + wn + j * 16 + m16;
            const float bv = bias[col];
#pragma unroll
            for (int i = 0; i < 4; ++i)
#pragma unroll
                for (int r = 0; r < 4; ++r)
                    C[(size_t)(m0 + wm + i * 16 + quad * 4 + r) * N + col] = acc[i][j][r] + bv;
        }
    }
}

// ---------------------------------------------------------------------------
// RoPE in place on bf16 qkv (q and k thirds). q scaled by QK_SCALE.
// ---------------------------------------------------------------------------
__global__ __launch_bounds__(256) void rope_bf16(bf16_t* __restrict__ qkv) {
    __shared__ float ctab[8][32];
    __shared__ float stab[8][32];
    const int tid = threadIdx.x;
    const int sl  = tid >> 5, j = tid & 31;
    const int s   = (int)((blockIdx.x * 8 + sl) & (SEQ - 1));
    const float freq = exp2f(-0.41524101186092029f * (float)j);  // 10000^(-j/32)
    float sn, cs;
    sincosf((float)s * freq, &sn, &cs);
    ctab[sl][j] = cs;
    stab[sl][j] = sn;
    __syncthreads();

    const int gid   = blockIdx.x * 256 + tid;
    const int m     = gid >> 5;
    const int rr    = gid & 31;
    const int which = rr >> 4;
    const int hh    = rr & 15;
    const float osc = (which == 0) ? QK_SCALE : 1.0f;

    bf16_t* p = qkv + (size_t)m * (3 * DIM_) + which * DIM_ + hh * HDIM;
    union { bf16_t e[64]; bf16x8 v[8]; } X, O;
#pragma unroll
    for (int i = 0; i < 8; ++i) X.v[i] = *(const bf16x8*)(p + i * 8);
#pragma unroll
    for (int t = 0; t < 32; ++t) {
        const float x1 = (float)X.e[2 * t];
        const float x2 = (float)X.e[2 * t + 1];
        const float c  = ctab[sl][t];
        const float s2 = stab[sl][t];
        O.e[t]      = (bf16_t)((x1 * c - x2 * s2) * osc);
        O.e[32 + t] = (bf16_t)((x1 * s2 + x2 * c) * osc);
    }
#pragma unroll
    for (int i = 0; i < 8; ++i) *(bf16x8*)(p + i * 8) = O.v[i];
}

// ---------------------------------------------------------------------------
// Flash attention, key-split waves. Direct-from-global K/V fragments (no LDS
// staging: fragments are wave-private and K/V per head is L2-resident) PLUS
// explicit REGISTER DOUBLE-BUFFER: 2x-unrolled ping-pong, tile t+1's loads
// issue before tile t's compute, so each load has a full compute phase
// (~8 QK MFMA + 16 exp2 + 16 PV MFMA) in flight before its waitcnt.
// No barriers in the main loop. LDS only for epilogue l/O reductions.
// ---------------------------------------------------------------------------
__global__ __launch_bounds__(256) void attn_mfma(const bf16_t* __restrict__ qkv,
                                                 const bf16_t* __restrict__ vt,
                                                 bf16_t* __restrict__ out) {
    __shared__ __align__(16) char smem[17664];
    float* Ored = (float*)smem;              // 16640 B
    float* Lred = (float*)(smem + 16640);    // 1024 B

    const int tid  = threadIdx.x;
    const int w    = tid >> 6;
    const int lane = tid & 63;
    const int m16  = lane & 15;
    const int quad = lane >> 4;
    const int bh   = blockIdx.y;
    const int b    = bh >> 4;
    const int hh   = bh & 15;
    const int q0   = blockIdx.x * 64;

    const size_t rs = 3 * DIM_;
    const bf16_t* qbase = qkv + (size_t)(b * SEQ) * rs + hh * HDIM;
    const bf16_t* kbase = qbase + DIM_;
    const bf16_t* vtg   = vt + (size_t)bh * 64 * SEQ;

    // Q fragments: qf[n][kt] = Q[q0+n*16+m16][kt*32+quad*8 ..+7]
    bf16x8 qf[4][2];
#pragma unroll
    for (int n = 0; n < 4; ++n)
#pragma unroll
        for (int kt = 0; kt < 2; ++kt)
            qf[n][kt] = *(const bf16x8*)(qbase + (size_t)(q0 + n * 16 + m16) * rs + kt * 32 + quad * 8);

    f32x4 o[4][4] = {};  // o[ds][n]: partial O^T over this wave's keys
    float lp[4] = {};    // per-lane partial l for q = n*16+m16

    // direct-fragment global pointers (advance by one tile per step)
    const bf16_t* kp = kbase + (size_t)(w * 16 + m16) * rs + quad * 8;
    const bf16_t* vp = vtg + (size_t)m16 * SEQ + w * 16 + quad * 4;
    const size_t kstep = (size_t)64 * rs;

#define TILE_COMPUTE(K0, K1, VV)                                                   \
    do {                                                                           \
        s16x4 pb[4];                                                               \
        _Pragma("unroll")                                                          \
        for (int n = 0; n < 4; ++n) {                                              \
            f32x4 c = {};                                                          \
            c = __builtin_amdgcn_mfma_f32_16x16x32_bf16(K0, qf[n][0], c, 0, 0, 0); \
            c = __builtin_amdgcn_mfma_f32_16x16x32_bf16(K1, qf[n][1], c, 0, 0, 0); \
            bf16x4 pv;                                                             \
            _Pragma("unroll")                                                      \
            for (int r = 0; r < 4; ++r) {                                          \
                const float pp = __builtin_amdgcn_exp2f(c[r]);                     \
                lp[n] += pp;                                                       \
                pv[r] = (bf16_t)pp;                                                \
            }                                                                      \
            pb[n] = as_s16x4(pv);                                                  \
        }                                                                          \
        __builtin_amdgcn_s_setprio(1);                                             \
        _Pragma("unroll")                                                          \
        for (int ds = 0; ds < 4; ++ds)                                             \
            _Pragma("unroll")                                                      \
            for (int n = 0; n < 4; ++n)                                            \
                o[ds][n] = __builtin_amdgcn_mfma_f32_16x16x16bf16_1k(               \
                    as_s16x4(VV[ds]), pb[n], o[ds][n], 0, 0, 0);                   \
        __builtin_amdgcn_s_setprio(0);                                             \
    } while (0)

    // prologue: tile 0 into buffer A
    bf16x8 kA0 = *(const bf16x8*)(kp);
    bf16x8 kA1 = *(const bf16x8*)(kp + 32);
    bf16x4 vA[4];
#pragma unroll
    for (int ds = 0; ds < 4; ++ds) vA[ds] = *(const bf16x4*)(vp + (size_t)ds * 16 * SEQ);
    kp += kstep; vp += 64;

    for (int t = 0; t < 32; t += 2) {
        // prefetch tile t+1 into buffer B (t <= 30, so always valid)
        bf16x8 kB0 = *(const bf16x8*)(kp);
        bf16x8 kB1 = *(const bf16x8*)(kp + 32);
        bf16x4 vB[4];
#pragma unroll
        for (int ds = 0; ds < 4; ++ds) vB[ds] = *(const bf16x4*)(vp + (size_t)ds * 16 * SEQ);
        kp += kstep; vp += 64;

        TILE_COMPUTE(kA0, kA1, vA);

        // prefetch tile t+2 into buffer A
        if (t + 2 < 32) {
            kA0 = *(const bf16x8*)(kp);
            kA1 = *(const bf16x8*)(kp + 32);
#pragma unroll
            for (int ds = 0; ds < 4; ++ds) vA[ds] = *(const bf16x4*)(vp + (size_t)ds * 16 * SEQ);
            kp += kstep; vp += 64;
        }

        TILE_COMPUTE(kB0, kB1, vB);
    }
#undef TILE_COMPUTE

    // ---- l reduction: over quads (shfl), then over waves (LDS) ----
#pragma unroll
    for (int n = 0; n < 4; ++n) {
        lp[n] += __shfl_xor(lp[n], 16);
        lp[n] += __shfl_xor(lp[n], 32);
    }
    if (quad == 0) {
#pragma unroll
        for (int n = 0; n < 4; ++n) Lred[w * 64 + n * 16 + m16] = lp[n];
    }
    __syncthreads();
    const float linv = 1.0f / (Lred[lane] + Lred[64 + lane] + Lred[128 + lane] + Lred[192 + lane]);

    // ---- O reduction: 4 phases; wave p owns dim-quarter p ----
    const size_t obase = (size_t)(b * SEQ + q0 + lane) * DIM_ + hh * HDIM;
#pragma unroll
    for (int p = 0; p < 4; ++p) {
        __syncthreads();
#pragma unroll
        for (int n = 0; n < 4; ++n)
#pragma unroll
            for (int r = 0; r < 4; ++r)
                Ored[w * 1040 + (quad * 4 + r) * 65 + n * 16 + m16] = o[p][n][r];
        __syncthreads();
        if (w == p) {
            union { bf16_t e[16]; bf16x8 v[2]; } ob;
#pragma unroll
            for (int d = 0; d < 16; ++d) {
                const float v = Ored[d * 65 + lane] + Ored[1040 + d * 65 + lane] +
                                Ored[2080 + d * 65 + lane] + Ored[3120 + d * 65 + lane];
                ob.e[d] = (bf16_t)(v * linv);
            }
            *(bf16x8*)(out + obase + p * 16)     = ob.v[0];
            *(bf16x8*)(out + obase + p * 16 + 8) = ob.v[1];
        }
    }
}

// ---------------------------------------------------------------------------
extern "C" void kernel_launch(void* const* d_in, const int* in_sizes, int n_in,
                              void* d_out, int out_size, void* d_ws, size_t ws_size,
                              hipStream_t stream) {
    const float* x     = (const float*)d_in[0];
    const float* w_qkv = (const float*)d_in[1];
    const float* w_out = (const float*)d_in[2];
    const float* b_out = (const float*)d_in[3];
    float* out = (float*)d_out;

    const int M = BATCH * SEQ;  // 4096

    bf16_t* qkv_b  = (bf16_t*)d_ws;                            // 4096x3072
    bf16_t* attn_b = qkv_b + (size_t)M * 3 * DIM_;             // 4096x1024
    bf16_t* vt_b   = attn_b + (size_t)M * DIM_;                // 32 heads x 64 x SEQ
    bf16_t* xb     = vt_b + (size_t)BATCH * NHEADS * HDIM * SEQ;
    bf16_t* wqkvb  = xb + (size_t)M * DIM_;
    bf16_t* woutb  = wqkvb + (size_t)3 * DIM_ * DIM_;

    // 0) cast x, w_qkv, w_out to bf16
    cast3<<<(XCNT + WQCNT + WOCNT) / (256 * 8), 256, 0, stream>>>(
        x, w_qkv, w_out, xb, wqkvb, woutb);

    // 1) qkv = x @ w_qkv^T  (q,k -> qkv_b; v -> vt_b transposed)
    gemm_lds<true><<<dim3(3 * DIM_ / 128, M / 128), 256, 0, stream>>>(
        xb, wqkvb, nullptr, qkv_b, vt_b, M, 3 * DIM_, DIM_);

    // 2) RoPE in place on q,k
    rope_bf16<<<(M * 2 * NHEADS) / 256, 256, 0, stream>>>(qkv_b);

    // 3) flash attention -> attn_b
    attn_mfma<<<dim3(SEQ / 64, BATCH * NHEADS), 256, 0, stream>>>(qkv_b, vt_b, attn_b);

    // 4) out = attn @ w_out^T + b_out (fp32)
    gemm_lds<false><<<dim3(DIM_ / 128, M / 128), 256, 0, stream>>>(
        attn_b, woutb, b_out, out, nullptr, M, DIM_, DIM_);
}

// Round 5
// 221.816 us; speedup vs baseline: 1.1312x; 1.1261x over previous
//
// R4 resubmission of R3 candidate (two prior runs failed at container level,
// no kernel verdict; source verified sound — see session journal).
#include <hip/hip_runtime.h>
#include <math.h>

typedef __bf16 bf16_t;
typedef bf16_t bf16x8 __attribute__((ext_vector_type(8)));
typedef bf16_t bf16x4 __attribute__((ext_vector_type(4)));
typedef short  s16x4  __attribute__((ext_vector_type(4)));
typedef float  f32x4  __attribute__((ext_vector_type(4)));

#define DIM_   1024
#define NHEADS 16
#define HDIM   64
#define SEQ    2048
#define BATCH  2

// log2(e)/8 : folded into q at RoPE time so attention softmax is exp2(s)
#define QK_SCALE 0.18033688011112042f

__device__ __forceinline__ s16x4 as_s16x4(bf16x4 v) {
    union { bf16x4 b; s16x4 s; } u; u.b = v; return u.s;
}

// async global->LDS, 16 B per lane; LDS dest = wave-uniform base + lane*16
__device__ __forceinline__ void gld16(const bf16_t* g, bf16_t* l) {
    __builtin_amdgcn_global_load_lds(
        (const __attribute__((address_space(1))) void*)g,
        (__attribute__((address_space(3))) void*)l, 16, 0, 0);
}

// ---------------------------------------------------------------------------
// Fused fp32->bf16 cast of x, w_qkv, w_out.
// ---------------------------------------------------------------------------
#define XCNT   (4096u * 1024u)
#define WQCNT  (3072u * 1024u)
#define WOCNT  (1024u * 1024u)
__global__ __launch_bounds__(256) void cast3(const float* __restrict__ s0,
                                             const float* __restrict__ s1,
                                             const float* __restrict__ s2,
                                             bf16_t* __restrict__ d0,
                                             bf16_t* __restrict__ d1,
                                             bf16_t* __restrict__ d2) {
    size_t i = ((size_t)blockIdx.x * 256 + threadIdx.x) * 8;
    const float* s; bf16_t* d; size_t off;
    if (i < XCNT)               { s = s0; d = d0; off = i; }
    else if (i < XCNT + WQCNT)  { s = s1; d = d1; off = i - XCNT; }
    else                        { s = s2; d = d2; off = i - XCNT - WQCNT; }
    float4 a = *(const float4*)(s + off);
    float4 b = *(const float4*)(s + off + 4);
    bf16x8 o = { (bf16_t)a.x, (bf16_t)a.y, (bf16_t)a.z, (bf16_t)a.w,
                 (bf16_t)b.x, (bf16_t)b.y, (bf16_t)b.z, (bf16_t)b.w };
    *(bf16x8*)(d + off) = o;
}

// ---------------------------------------------------------------------------
// m97-style bf16 GEMM: 128x128 tile, BK=32, global_load_lds width-16 staging,
// unpadded LDS, b128 frag reads. Used for the QKV GEMM (768 blocks = 3/CU).
// ---------------------------------------------------------------------------
template <bool QKV>
__global__ __launch_bounds__(256) void gemm_lds(const bf16_t* __restrict__ A,
                                                const bf16_t* __restrict__ B,
                                                const float* __restrict__ bias,
                                                void* __restrict__ Cout,
                                                bf16_t* __restrict__ vt,
                                                int M, int N, int K) {
    __shared__ __align__(16) bf16_t As[128 * 32];
    __shared__ __align__(16) bf16_t Bs[128 * 32];
    const int tid  = threadIdx.x;
    const int m0   = blockIdx.y * 128;
    const int n0   = blockIdx.x * 128;
    const int w    = tid >> 6;
    const int lane = tid & 63;
    const int m16  = lane & 15;
    const int quad = lane >> 4;
    const int wm   = (w >> 1) * 64;
    const int wn   = (w & 1) * 64;
    const int lrow = lane >> 2;
    const int lcol = (lane & 3) * 8;

    const bf16_t* pa0 = A + (size_t)(m0 + w * 16 + lrow) * K + lcol;
    const bf16_t* pb0 = B + (size_t)(n0 + w * 16 + lrow) * K + lcol;
    bf16_t* lA0 = &As[(w * 16) * 32];
    bf16_t* lA1 = &As[(64 + w * 16) * 32];
    bf16_t* lB0 = &Bs[(w * 16) * 32];
    bf16_t* lB1 = &Bs[(64 + w * 16) * 32];

    f32x4 acc[4][4] = {};

    for (int k0 = 0; k0 < K; k0 += 32) {
        __syncthreads();
        gld16(pa0 + k0, lA0);
        gld16(pa0 + (size_t)64 * K + k0, lA1);
        gld16(pb0 + k0, lB0);
        gld16(pb0 + (size_t)64 * K + k0, lB1);
        __syncthreads();

        bf16x8 af[4], bfr[4];
#pragma unroll
        for (int i = 0; i < 4; ++i)
            af[i] = *(const bf16x8*)(&As[(wm + i * 16 + m16) * 32 + quad * 8]);
#pragma unroll
        for (int j = 0; j < 4; ++j)
            bfr[j] = *(const bf16x8*)(&Bs[(wn + j * 16 + m16) * 32 + quad * 8]);
#pragma unroll
        for (int i = 0; i < 4; ++i)
#pragma unroll
            for (int j = 0; j < 4; ++j)
                acc[i][j] = __builtin_amdgcn_mfma_f32_16x16x32_bf16(af[i], bfr[j], acc[i][j], 0, 0, 0);
    }

    if (QKV && n0 >= 2 * DIM_) {
        const int b      = m0 >> 11;
        const int s_base = (m0 & (SEQ - 1)) + wm;
#pragma unroll
        for (int j = 0; j < 4; ++j) {
            const int cit = wn + j * 16 + m16;
            const int h   = ((n0 - 2 * DIM_) >> 6) + (cit >> 6);
            const int d   = cit & 63;
            bf16_t* vrow = vt + ((size_t)(b * 16 + h) * 64 + d) * SEQ + s_base;
#pragma unroll
            for (int i = 0; i < 4; ++i) {
                bf16x4 ov = { (bf16_t)acc[i][j][0], (bf16_t)acc[i][j][1],
                              (bf16_t)acc[i][j][2], (bf16_t)acc[i][j][3] };
                *(bf16x4*)(vrow + i * 16 + quad * 4) = ov;
            }
        }
    } else if (QKV) {
        bf16_t* C = (bf16_t*)Cout;
#pragma unroll
        for (int i = 0; i < 4; ++i)
#pragma unroll
            for (int j = 0; j < 4; ++j) {
                const int col = n0 + wn + j * 16 + m16;
#pragma unroll
                for (int r = 0; r < 4; ++r)
                    C[(size_t)(m0 + wm + i * 16 + quad * 4 + r) * N + col] = (bf16_t)acc[i][j][r];
            }
    } else {
        float* C = (float*)Cout;
#pragma unroll
        for (int j = 0; j < 4; ++j) {
            const int col = n0 + wn + j * 16 + m16;
            const float bv = bias[col];
#pragma unroll
            for (int i = 0; i < 4; ++i)
#pragma unroll
                for (int r = 0; r < 4; ++r)
                    C[(size_t)(m0 + wm + i * 16 + quad * 4 + r) * N + col] = acc[i][j][r] + bv;
        }
    }
}

// ---------------------------------------------------------------------------
// Output GEMM, 128x64 tile: C(4096x1024) = A(4096x1024) @ B(1024x1024)^T + b.
// The 128x128 version launched exactly 256 blocks = 1 block/CU = 1 wave/SIMD:
// grid-capped occupancy, the barrier-locked loop has zero TLP. 128x64 doubles
// the grid to 512 (2 blocks/CU, 2 waves/SIMD) and halves acc VGPRs.
// Waves 2x2: wave w owns rows (w>>1)*64, cols (w&1)*32. acc[4][2].
// ---------------------------------------------------------------------------
__global__ __launch_bounds__(256) void gemm_out64(const bf16_t* __restrict__ A,
                                                  const bf16_t* __restrict__ B,
                                                  const float* __restrict__ bias,
                                                  float* __restrict__ C,
                                                  int M, int N, int K) {
    __shared__ __align__(16) bf16_t As[128 * 32];
    __shared__ __align__(16) bf16_t Bs[64 * 32];
    const int tid  = threadIdx.x;
    const int m0   = blockIdx.y * 128;
    const int n0   = blockIdx.x * 64;
    const int w    = tid >> 6;
    const int lane = tid & 63;
    const int m16  = lane & 15;
    const int quad = lane >> 4;
    const int wm   = (w >> 1) * 64;
    const int wn   = (w & 1) * 32;
    const int lrow = lane >> 2;
    const int lcol = (lane & 3) * 8;

    const bf16_t* pa0 = A + (size_t)(m0 + w * 16 + lrow) * K + lcol;
    const bf16_t* pb0 = B + (size_t)(n0 + w * 16 + lrow) * K + lcol;
    bf16_t* lA0 = &As[(w * 16) * 32];
    bf16_t* lA1 = &As[(64 + w * 16) * 32];
    bf16_t* lB0 = &Bs[(w * 16) * 32];

    f32x4 acc[4][2] = {};

    for (int k0 = 0; k0 < K; k0 += 32) {
        __syncthreads();
        gld16(pa0 + k0, lA0);
        gld16(pa0 + (size_t)64 * K + k0, lA1);
        gld16(pb0 + k0, lB0);
        __syncthreads();

        bf16x8 af[4], bfr[2];
#pragma unroll
        for (int i = 0; i < 4; ++i)
            af[i] = *(const bf16x8*)(&As[(wm + i * 16 + m16) * 32 + quad * 8]);
#pragma unroll
        for (int j = 0; j < 2; ++j)
            bfr[j] = *(const bf16x8*)(&Bs[(wn + j * 16 + m16) * 32 + quad * 8]);
#pragma unroll
        for (int i = 0; i < 4; ++i)
#pragma unroll
            for (int j = 0; j < 2; ++j)
                acc[i][j] = __builtin_amdgcn_mfma_f32_16x16x32_bf16(af[i], bfr[j], acc[i][j], 0, 0, 0);
    }

#pragma unroll
    for (int j = 0; j < 2; ++j) {
        const int col = n0 + wn + j * 16 + m16;
        const float bv = bias[col];
#pragma unroll
        for (int i = 0; i < 4; ++i)
#pragma unroll
            for (int r = 0; r < 4; ++r)
                C[(size_t)(m0 + wm + i * 16 + quad * 4 + r) * N + col] = acc[i][j][r] + bv;
    }
}

// ---------------------------------------------------------------------------
// RoPE in place on bf16 qkv (q and k thirds). q scaled by QK_SCALE.
// ---------------------------------------------------------------------------
__global__ __launch_bounds__(256) void rope_bf16(bf16_t* __restrict__ qkv) {
    __shared__ float ctab[8][32];
    __shared__ float stab[8][32];
    const int tid = threadIdx.x;
    const int sl  = tid >> 5, j = tid & 31;
    const int s   = (int)((blockIdx.x * 8 + sl) & (SEQ - 1));
    const float freq = exp2f(-0.41524101186092029f * (float)j);  // 10000^(-j/32)
    float sn, cs;
    sincosf((float)s * freq, &sn, &cs);
    ctab[sl][j] = cs;
    stab[sl][j] = sn;
    __syncthreads();

    const int gid   = blockIdx.x * 256 + tid;
    const int m     = gid >> 5;
    const int rr    = gid & 31;
    const int which = rr >> 4;
    const int hh    = rr & 15;
    const float osc = (which == 0) ? QK_SCALE : 1.0f;

    bf16_t* p = qkv + (size_t)m * (3 * DIM_) + which * DIM_ + hh * HDIM;
    union { bf16_t e[64]; bf16x8 v[8]; } X, O;
#pragma unroll
    for (int i = 0; i < 8; ++i) X.v[i] = *(const bf16x8*)(p + i * 8);
#pragma unroll
    for (int t = 0; t < 32; ++t) {
        const float x1 = (float)X.e[2 * t];
        const float x2 = (float)X.e[2 * t + 1];
        const float c  = ctab[sl][t];
        const float s2 = stab[sl][t];
        O.e[t]      = (bf16_t)((x1 * c - x2 * s2) * osc);
        O.e[32 + t] = (bf16_t)((x1 * s2 + x2 * c) * osc);
    }
#pragma unroll
    for (int i = 0; i < 8; ++i) *(bf16x8*)(p + i * 8) = O.v[i];
}

// ---------------------------------------------------------------------------
// Flash attention, key-split waves (verified 83.3 us structure): coalesced
// register-staged LDS tiles, register double-buffer across the ds_write
// barrier. Direct-global variants (R1/R2) measured WORSE (105 us): the
// fragment access pattern is a 16-segment scatter and the per-XCD concurrent
// K/V working set (16 MB) thrashes L2 -- keep the coalesced staging.
// ---------------------------------------------------------------------------
__global__ __launch_bounds__(256) void attn_mfma(const bf16_t* __restrict__ qkv,
                                                 const bf16_t* __restrict__ vt,
                                                 bf16_t* __restrict__ out) {
    __shared__ __align__(16) char smem[18432];
    bf16_t* Ks   = (bf16_t*)smem;             // 64 x 72 bf16 (9216 B)
    bf16_t* Vt   = (bf16_t*)(smem + 9216);    // 64 x 72 bf16 (9216 B)
    float*  Ored = (float*)smem;              // epilogue alias: 16640 B
    float*  Lred = (float*)(smem + 16640);    // 1024 B

    const int tid  = threadIdx.x;
    const int w    = tid >> 6;
    const int lane = tid & 63;
    const int m16  = lane & 15;
    const int quad = lane >> 4;
    const int bh   = blockIdx.y;
    const int b    = bh >> 4;
    const int hh   = bh & 15;
    const int q0   = blockIdx.x * 64;

    const size_t rs = 3 * DIM_;
    const bf16_t* qbase = qkv + (size_t)(b * SEQ) * rs + hh * HDIM;
    const bf16_t* kbase = qbase + DIM_;
    const bf16_t* vtg   = vt + (size_t)bh * 64 * SEQ;

    // Q fragments: qf[n][kt] = Q[q0+n*16+m16][kt*32+quad*8 ..+7]
    bf16x8 qf[4][2];
#pragma unroll
    for (int n = 0; n < 4; ++n)
#pragma unroll
        for (int kt = 0; kt < 2; ++kt)
            qf[n][kt] = *(const bf16x8*)(qbase + (size_t)(q0 + n * 16 + m16) * rs + kt * 32 + quad * 8);

    f32x4 o[4][4] = {};  // o[ds][n]: partial O^T over this wave's keys
    float lp[4] = {};    // per-lane partial l for q = n*16+m16

    // coalesced staging geometry: 256 threads cover 32 rows/pass
    const int srow = tid >> 3;          // 0..31
    const int sc8  = (tid & 7) * 8;     // 0..56

    // staged registers: tile t's K rows (srow, srow+32) and V^T rows
    bf16x8 kreg[2], vreg[2];
#pragma unroll
    for (int p = 0; p < 2; ++p) {
        const int row = srow + p * 32;
        kreg[p] = *(const bf16x8*)(kbase + (size_t)row * rs + sc8);
        vreg[p] = *(const bf16x8*)(vtg + (size_t)row * SEQ + sc8);
    }

    for (int t = 0; t < 32; ++t) {
        __syncthreads();   // previous tile's compute done; LDS reusable
#pragma unroll
        for (int p = 0; p < 2; ++p) {
            const int row = srow + p * 32;
            *(bf16x8*)(&Ks[row * 72 + sc8]) = kreg[p];
            *(bf16x8*)(&Vt[row * 72 + sc8]) = vreg[p];
        }
        __syncthreads();   // staged tile visible to all waves

        // issue next tile's global loads; they overlap the compute below
        if (t < 31) {
            const size_t k0n = (size_t)(t + 1) * 64;
#pragma unroll
            for (int p = 0; p < 2; ++p) {
                const int row = srow + p * 32;
                kreg[p] = *(const bf16x8*)(kbase + (k0n + row) * rs + sc8);
                vreg[p] = *(const bf16x8*)(vtg + (size_t)row * SEQ + k0n + sc8);
            }
        }

        // ---- compute tile t ----
        bf16x8 ak0 = *(const bf16x8*)(&Ks[(w * 16 + m16) * 72 + 0 * 32 + quad * 8]);
        bf16x8 ak1 = *(const bf16x8*)(&Ks[(w * 16 + m16) * 72 + 1 * 32 + quad * 8]);
        bf16x4 va[4];
#pragma unroll
        for (int ds = 0; ds < 4; ++ds)
            va[ds] = *(const bf16x4*)(&Vt[(ds * 16 + m16) * 72 + w * 16 + quad * 4]);

        s16x4 pb[4];
#pragma unroll
        for (int n = 0; n < 4; ++n) {
            f32x4 c = {};
            c = __builtin_amdgcn_mfma_f32_16x16x32_bf16(ak0, qf[n][0], c, 0, 0, 0);
            c = __builtin_amdgcn_mfma_f32_16x16x32_bf16(ak1, qf[n][1], c, 0, 0, 0);
            bf16x4 pv;
#pragma unroll
            for (int r = 0; r < 4; ++r) {
                const float p = __builtin_amdgcn_exp2f(c[r]);
                lp[n] += p;
                pv[r] = (bf16_t)p;
            }
            pb[n] = as_s16x4(pv);
        }

#pragma unroll
        for (int ds = 0; ds < 4; ++ds)
#pragma unroll
            for (int n = 0; n < 4; ++n)
                o[ds][n] = __builtin_amdgcn_mfma_f32_16x16x16bf16_1k(as_s16x4(va[ds]), pb[n], o[ds][n], 0, 0, 0);
    }

    // ---- l reduction: over quads (shfl), then over waves (LDS) ----
#pragma unroll
    for (int n = 0; n < 4; ++n) {
        lp[n] += __shfl_xor(lp[n], 16);
        lp[n] += __shfl_xor(lp[n], 32);
    }
    __syncthreads();   // all waves done with staging LDS before aliasing
    if (quad == 0) {
#pragma unroll
        for (int n = 0; n < 4; ++n) Lred[w * 64 + n * 16 + m16] = lp[n];
    }
    __syncthreads();
    const float linv = 1.0f / (Lred[lane] + Lred[64 + lane] + Lred[128 + lane] + Lred[192 + lane]);

    // ---- O reduction: 4 phases; wave p owns dim-quarter p ----
    const size_t obase = (size_t)(b * SEQ + q0 + lane) * DIM_ + hh * HDIM;
#pragma unroll
    for (int p = 0; p < 4; ++p) {
        __syncthreads();
#pragma unroll
        for (int n = 0; n < 4; ++n)
#pragma unroll
            for (int r = 0; r < 4; ++r)
                Ored[w * 1040 + (quad * 4 + r) * 65 + n * 16 + m16] = o[p][n][r];
        __syncthreads();
        if (w == p) {
            union { bf16_t e[16]; bf16x8 v[2]; } ob;
#pragma unroll
            for (int d = 0; d < 16; ++d) {
                const float v = Ored[d * 65 + lane] + Ored[1040 + d * 65 + lane] +
                                Ored[2080 + d * 65 + lane] + Ored[3120 + d * 65 + lane];
                ob.e[d] = (bf16_t)(v * linv);
            }
            *(bf16x8*)(out + obase + p * 16)     = ob.v[0];
            *(bf16x8*)(out + obase + p * 16 + 8) = ob.v[1];
        }
    }
}

// ---------------------------------------------------------------------------
extern "C" void kernel_launch(void* const* d_in, const int* in_sizes, int n_in,
                              void* d_out, int out_size, void* d_ws, size_t ws_size,
                              hipStream_t stream) {
    const float* x     = (const float*)d_in[0];
    const float* w_qkv = (const float*)d_in[1];
    const float* w_out = (const float*)d_in[2];
    const float* b_out = (const float*)d_in[3];
    float* out = (float*)d_out;

    const int M = BATCH * SEQ;  // 4096

    bf16_t* qkv_b  = (bf16_t*)d_ws;                            // 4096x3072
    bf16_t* attn_b = qkv_b + (size_t)M * 3 * DIM_;             // 4096x1024
    bf16_t* vt_b   = attn_b + (size_t)M * DIM_;                // 32 heads x 64 x SEQ
    bf16_t* xb     = vt_b + (size_t)BATCH * NHEADS * HDIM * SEQ;
    bf16_t* wqkvb  = xb + (size_t)M * DIM_;
    bf16_t* woutb  = wqkvb + (size_t)3 * DIM_ * DIM_;

    // 0) cast x, w_qkv, w_out to bf16
    cast3<<<(XCNT + WQCNT + WOCNT) / (256 * 8), 256, 0, stream>>>(
        x, w_qkv, w_out, xb, wqkvb, woutb);

    // 1) qkv = x @ w_qkv^T  (q,k -> qkv_b; v -> vt_b transposed)
    gemm_lds<true><<<dim3(3 * DIM_ / 128, M / 128), 256, 0, stream>>>(
        xb, wqkvb, nullptr, qkv_b, vt_b, M, 3 * DIM_, DIM_);

    // 2) RoPE in place on q,k
    rope_bf16<<<(M * 2 * NHEADS) / 256, 256, 0, stream>>>(qkv_b);

    // 3) flash attention -> attn_b
    attn_mfma<<<dim3(SEQ / 64, BATCH * NHEADS), 256, 0, stream>>>(qkv_b, vt_b, attn_b);

    // 4) out = attn @ w_out^T + b_out (fp32), 128x64 tiles -> 512 blocks (2/CU)
    gemm_out64<<<dim3(DIM_ / 64, M / 128), 256, 0, stream>>>(
        attn_b, woutb, b_out, out, M, DIM_, DIM_);
}

// Round 6
// 215.646 us; speedup vs baseline: 1.1635x; 1.0286x over previous
//
#include <hip/hip_runtime.h>
#include <math.h>

typedef __bf16 bf16_t;
typedef bf16_t bf16x8 __attribute__((ext_vector_type(8)));
typedef bf16_t bf16x4 __attribute__((ext_vector_type(4)));
typedef short  s16x4  __attribute__((ext_vector_type(4)));
typedef float  f32x4  __attribute__((ext_vector_type(4)));

#define DIM_   1024
#define NHEADS 16
#define HDIM   64
#define SEQ    2048
#define BATCH  2

// log2(e)/8 : folded into q at RoPE time so attention softmax is exp2(s)
#define QK_SCALE 0.18033688011112042f

__device__ __forceinline__ s16x4 as_s16x4(bf16x4 v) {
    union { bf16x4 b; s16x4 s; } u; u.b = v; return u.s;
}

// async global->LDS, 16 B per lane; LDS dest = wave-uniform base + lane*16
__device__ __forceinline__ void gld16(const bf16_t* g, bf16_t* l) {
    __builtin_amdgcn_global_load_lds(
        (const __attribute__((address_space(1))) void*)g,
        (__attribute__((address_space(3))) void*)l, 16, 0, 0);
}

// ---------------------------------------------------------------------------
// Fused fp32->bf16 cast of x, w_qkv, w_out.
// ---------------------------------------------------------------------------
#define XCNT   (4096u * 1024u)
#define WQCNT  (3072u * 1024u)
#define WOCNT  (1024u * 1024u)
__global__ __launch_bounds__(256) void cast3(const float* __restrict__ s0,
                                             const float* __restrict__ s1,
                                             const float* __restrict__ s2,
                                             bf16_t* __restrict__ d0,
                                             bf16_t* __restrict__ d1,
                                             bf16_t* __restrict__ d2) {
    size_t i = ((size_t)blockIdx.x * 256 + threadIdx.x) * 8;
    const float* s; bf16_t* d; size_t off;
    if (i < XCNT)               { s = s0; d = d0; off = i; }
    else if (i < XCNT + WQCNT)  { s = s1; d = d1; off = i - XCNT; }
    else                        { s = s2; d = d2; off = i - XCNT - WQCNT; }
    float4 a = *(const float4*)(s + off);
    float4 b = *(const float4*)(s + off + 4);
    bf16x8 o = { (bf16_t)a.x, (bf16_t)a.y, (bf16_t)a.z, (bf16_t)a.w,
                 (bf16_t)b.x, (bf16_t)b.y, (bf16_t)b.z, (bf16_t)b.w };
    *(bf16x8*)(d + off) = o;
}

// ---------------------------------------------------------------------------
// m97-style bf16 GEMM: 128x128 tile, BK=32, global_load_lds width-16 staging,
// unpadded LDS, b128 frag reads. Used for the QKV GEMM (768 blocks = 3/CU).
// ---------------------------------------------------------------------------
template <bool QKV>
__global__ __launch_bounds__(256) void gemm_lds(const bf16_t* __restrict__ A,
                                                const bf16_t* __restrict__ B,
                                                const float* __restrict__ bias,
                                                void* __restrict__ Cout,
                                                bf16_t* __restrict__ vt,
                                                int M, int N, int K) {
    __shared__ __align__(16) bf16_t As[128 * 32];
    __shared__ __align__(16) bf16_t Bs[128 * 32];
    const int tid  = threadIdx.x;
    const int m0   = blockIdx.y * 128;
    const int n0   = blockIdx.x * 128;
    const int w    = tid >> 6;
    const int lane = tid & 63;
    const int m16  = lane & 15;
    const int quad = lane >> 4;
    const int wm   = (w >> 1) * 64;
    const int wn   = (w & 1) * 64;
    const int lrow = lane >> 2;
    const int lcol = (lane & 3) * 8;

    const bf16_t* pa0 = A + (size_t)(m0 + w * 16 + lrow) * K + lcol;
    const bf16_t* pb0 = B + (size_t)(n0 + w * 16 + lrow) * K + lcol;
    bf16_t* lA0 = &As[(w * 16) * 32];
    bf16_t* lA1 = &As[(64 + w * 16) * 32];
    bf16_t* lB0 = &Bs[(w * 16) * 32];
    bf16_t* lB1 = &Bs[(64 + w * 16) * 32];

    f32x4 acc[4][4] = {};

    for (int k0 = 0; k0 < K; k0 += 32) {
        __syncthreads();
        gld16(pa0 + k0, lA0);
        gld16(pa0 + (size_t)64 * K + k0, lA1);
        gld16(pb0 + k0, lB0);
        gld16(pb0 + (size_t)64 * K + k0, lB1);
        __syncthreads();

        bf16x8 af[4], bfr[4];
#pragma unroll
        for (int i = 0; i < 4; ++i)
            af[i] = *(const bf16x8*)(&As[(wm + i * 16 + m16) * 32 + quad * 8]);
#pragma unroll
        for (int j = 0; j < 4; ++j)
            bfr[j] = *(const bf16x8*)(&Bs[(wn + j * 16 + m16) * 32 + quad * 8]);
#pragma unroll
        for (int i = 0; i < 4; ++i)
#pragma unroll
            for (int j = 0; j < 4; ++j)
                acc[i][j] = __builtin_amdgcn_mfma_f32_16x16x32_bf16(af[i], bfr[j], acc[i][j], 0, 0, 0);
    }

    if (QKV && n0 >= 2 * DIM_) {
        const int b      = m0 >> 11;
        const int s_base = (m0 & (SEQ - 1)) + wm;
#pragma unroll
        for (int j = 0; j < 4; ++j) {
            const int cit = wn + j * 16 + m16;
            const int h   = ((n0 - 2 * DIM_) >> 6) + (cit >> 6);
            const int d   = cit & 63;
            bf16_t* vrow = vt + ((size_t)(b * 16 + h) * 64 + d) * SEQ + s_base;
#pragma unroll
            for (int i = 0; i < 4; ++i) {
                bf16x4 ov = { (bf16_t)acc[i][j][0], (bf16_t)acc[i][j][1],
                              (bf16_t)acc[i][j][2], (bf16_t)acc[i][j][3] };
                *(bf16x4*)(vrow + i * 16 + quad * 4) = ov;
            }
        }
    } else if (QKV) {
        bf16_t* C = (bf16_t*)Cout;
#pragma unroll
        for (int i = 0; i < 4; ++i)
#pragma unroll
            for (int j = 0; j < 4; ++j) {
                const int col = n0 + wn + j * 16 + m16;
#pragma unroll
                for (int r = 0; r < 4; ++r)
                    C[(size_t)(m0 + wm + i * 16 + quad * 4 + r) * N + col] = (bf16_t)acc[i][j][r];
            }
    } else {
        float* C = (float*)Cout;
#pragma unroll
        for (int j = 0; j < 4; ++j) {
            const int col = n0 + wn + j * 16 + m16;
            const float bv = bias[col];
#pragma unroll
            for (int i = 0; i < 4; ++i)
#pragma unroll
                for (int r = 0; r < 4; ++r)
                    C[(size_t)(m0 + wm + i * 16 + quad * 4 + r) * N + col] = acc[i][j][r] + bv;
        }
    }
}

// ---------------------------------------------------------------------------
// Output GEMM, 128x64 tile (R5: 512 blocks = 2/CU, small win — keep).
// ---------------------------------------------------------------------------
__global__ __launch_bounds__(256) void gemm_out64(const bf16_t* __restrict__ A,
                                                  const bf16_t* __restrict__ B,
                                                  const float* __restrict__ bias,
                                                  float* __restrict__ C,
                                                  int M, int N, int K) {
    __shared__ __align__(16) bf16_t As[128 * 32];
    __shared__ __align__(16) bf16_t Bs[64 * 32];
    const int tid  = threadIdx.x;
    const int m0   = blockIdx.y * 128;
    const int n0   = blockIdx.x * 64;
    const int w    = tid >> 6;
    const int lane = tid & 63;
    const int m16  = lane & 15;
    const int quad = lane >> 4;
    const int wm   = (w >> 1) * 64;
    const int wn   = (w & 1) * 32;
    const int lrow = lane >> 2;
    const int lcol = (lane & 3) * 8;

    const bf16_t* pa0 = A + (size_t)(m0 + w * 16 + lrow) * K + lcol;
    const bf16_t* pb0 = B + (size_t)(n0 + w * 16 + lrow) * K + lcol;
    bf16_t* lA0 = &As[(w * 16) * 32];
    bf16_t* lA1 = &As[(64 + w * 16) * 32];
    bf16_t* lB0 = &Bs[(w * 16) * 32];

    f32x4 acc[4][2] = {};

    for (int k0 = 0; k0 < K; k0 += 32) {
        __syncthreads();
        gld16(pa0 + k0, lA0);
        gld16(pa0 + (size_t)64 * K + k0, lA1);
        gld16(pb0 + k0, lB0);
        __syncthreads();

        bf16x8 af[4], bfr[2];
#pragma unroll
        for (int i = 0; i < 4; ++i)
            af[i] = *(const bf16x8*)(&As[(wm + i * 16 + m16) * 32 + quad * 8]);
#pragma unroll
        for (int j = 0; j < 2; ++j)
            bfr[j] = *(const bf16x8*)(&Bs[(wn + j * 16 + m16) * 32 + quad * 8]);
#pragma unroll
        for (int i = 0; i < 4; ++i)
#pragma unroll
            for (int j = 0; j < 2; ++j)
                acc[i][j] = __builtin_amdgcn_mfma_f32_16x16x32_bf16(af[i], bfr[j], acc[i][j], 0, 0, 0);
    }

#pragma unroll
    for (int j = 0; j < 2; ++j) {
        const int col = n0 + wn + j * 16 + m16;
        const float bv = bias[col];
#pragma unroll
        for (int i = 0; i < 4; ++i)
#pragma unroll
            for (int r = 0; r < 4; ++r)
                C[(size_t)(m0 + wm + i * 16 + quad * 4 + r) * N + col] = acc[i][j][r] + bv;
    }
}

// ---------------------------------------------------------------------------
// RoPE in place on bf16 qkv (q and k thirds). q scaled by QK_SCALE.
// ---------------------------------------------------------------------------
__global__ __launch_bounds__(256) void rope_bf16(bf16_t* __restrict__ qkv) {
    __shared__ float ctab[8][32];
    __shared__ float stab[8][32];
    const int tid = threadIdx.x;
    const int sl  = tid >> 5, j = tid & 31;
    const int s   = (int)((blockIdx.x * 8 + sl) & (SEQ - 1));
    const float freq = exp2f(-0.41524101186092029f * (float)j);  // 10000^(-j/32)
    float sn, cs;
    sincosf((float)s * freq, &sn, &cs);
    ctab[sl][j] = cs;
    stab[sl][j] = sn;
    __syncthreads();

    const int gid   = blockIdx.x * 256 + tid;
    const int m     = gid >> 5;
    const int rr    = gid & 31;
    const int which = rr >> 4;
    const int hh    = rr & 15;
    const float osc = (which == 0) ? QK_SCALE : 1.0f;

    bf16_t* p = qkv + (size_t)m * (3 * DIM_) + which * DIM_ + hh * HDIM;
    union { bf16_t e[64]; bf16x8 v[8]; } X, O;
#pragma unroll
    for (int i = 0; i < 8; ++i) X.v[i] = *(const bf16x8*)(p + i * 8);
#pragma unroll
    for (int t = 0; t < 32; ++t) {
        const float x1 = (float)X.e[2 * t];
        const float x2 = (float)X.e[2 * t + 1];
        const float c  = ctab[sl][t];
        const float s2 = stab[sl][t];
        O.e[t]      = (bf16_t)((x1 * c - x2 * s2) * osc);
        O.e[32 + t] = (bf16_t)((x1 * s2 + x2 * c) * osc);
    }
#pragma unroll
    for (int i = 0; i < 8; ++i) *(bf16x8*)(p + i * 8) = O.v[i];
}

// ---------------------------------------------------------------------------
// Flash attention, key-split waves. R6: LDS DOUBLE-BUFFER, ONE barrier/tile.
// R0 structure had 2 barriers/tile (write into the single buffer had to wait
// for all waves' compute). With buf0/buf1: compute tile t from buf[t&1] while
// writing tile t+1 into buf[~t&1]; barrier only at iteration end. Counters
// said wall = 1.75x VALU-issue floor => stall-bound; this removes half the
// rendezvous. Coalesced reg-staged loads kept (R1/R2 direct-global: -25%).
// setprio(1) wraps the PV MFMA cluster (m191: attn-positive, multi-block CU).
// ---------------------------------------------------------------------------
__global__ __launch_bounds__(256) void attn_mfma(const bf16_t* __restrict__ qkv,
                                                 const bf16_t* __restrict__ vt,
                                                 bf16_t* __restrict__ out) {
    __shared__ __align__(16) char smem[37888];
    bf16_t* Ks0  = (bf16_t*)smem;              // 64 x 72 bf16 (9216 B)
    bf16_t* Vt0  = (bf16_t*)(smem + 9216);
    bf16_t* Ks1  = (bf16_t*)(smem + 18432);
    bf16_t* Vt1  = (bf16_t*)(smem + 27648);
    float*  Ored = (float*)smem;               // epilogue alias: 16640 B
    float*  Lred = (float*)(smem + 36864);     // 1024 B

    const int tid  = threadIdx.x;
    const int w    = tid >> 6;
    const int lane = tid & 63;
    const int m16  = lane & 15;
    const int quad = lane >> 4;
    const int bh   = blockIdx.y;
    const int b    = bh >> 4;
    const int hh   = bh & 15;
    const int q0   = blockIdx.x * 64;

    const size_t rs = 3 * DIM_;
    const bf16_t* qbase = qkv + (size_t)(b * SEQ) * rs + hh * HDIM;
    const bf16_t* kbase = qbase + DIM_;
    const bf16_t* vtg   = vt + (size_t)bh * 64 * SEQ;

    // Q fragments: qf[n][kt] = Q[q0+n*16+m16][kt*32+quad*8 ..+7]
    bf16x8 qf[4][2];
#pragma unroll
    for (int n = 0; n < 4; ++n)
#pragma unroll
        for (int kt = 0; kt < 2; ++kt)
            qf[n][kt] = *(const bf16x8*)(qbase + (size_t)(q0 + n * 16 + m16) * rs + kt * 32 + quad * 8);

    f32x4 o[4][4] = {};  // o[ds][n]: partial O^T over this wave's keys
    float lp[4] = {};    // per-lane partial l for q = n*16+m16

    // coalesced staging geometry: 256 threads cover 32 rows/pass
    const int srow = tid >> 3;          // 0..31
    const int sc8  = (tid & 7) * 8;     // 0..56

    bf16x8 kreg[2], vreg[2];

    // prologue: tile 0 -> regs -> buf0 -> barrier
#pragma unroll
    for (int p = 0; p < 2; ++p) {
        const int row = srow + p * 32;
        kreg[p] = *(const bf16x8*)(kbase + (size_t)row * rs + sc8);
        vreg[p] = *(const bf16x8*)(vtg + (size_t)row * SEQ + sc8);
    }
#pragma unroll
    for (int p = 0; p < 2; ++p) {
        const int row = srow + p * 32;
        *(bf16x8*)(&Ks0[row * 72 + sc8]) = kreg[p];
        *(bf16x8*)(&Vt0[row * 72 + sc8]) = vreg[p];
    }
    __syncthreads();

    // body(T): compute from KS/VS; prefetch T+1 to regs; write regs -> KSN/VSN
#define ATTN_BODY(T, KS, VS, KSN, VSN)                                             \
    do {                                                                           \
        const int tt = (T);                                                        \
        if (tt < 31) {                                                             \
            const size_t k0n = (size_t)(tt + 1) * 64;                              \
            _Pragma("unroll")                                                      \
            for (int p = 0; p < 2; ++p) {                                          \
                const int row = srow + p * 32;                                     \
                kreg[p] = *(const bf16x8*)(kbase + (k0n + row) * rs + sc8);        \
                vreg[p] = *(const bf16x8*)(vtg + (size_t)row * SEQ + k0n + sc8);   \
            }                                                                      \
        }                                                                          \
        bf16x8 ak0 = *(const bf16x8*)(&KS[(w * 16 + m16) * 72 + 0 * 32 + quad * 8]); \
        bf16x8 ak1 = *(const bf16x8*)(&KS[(w * 16 + m16) * 72 + 1 * 32 + quad * 8]); \
        bf16x4 va[4];                                                              \
        _Pragma("unroll")                                                          \
        for (int ds = 0; ds < 4; ++ds)                                             \
            va[ds] = *(const bf16x4*)(&VS[(ds * 16 + m16) * 72 + w * 16 + quad * 4]); \
        s16x4 pb[4];                                                               \
        _Pragma("unroll")                                                          \
        for (int n = 0; n < 4; ++n) {                                              \
            f32x4 c = {};                                                          \
            c = __builtin_amdgcn_mfma_f32_16x16x32_bf16(ak0, qf[n][0], c, 0, 0, 0); \
            c = __builtin_amdgcn_mfma_f32_16x16x32_bf16(ak1, qf[n][1], c, 0, 0, 0); \
            bf16x4 pv;                                                             \
            _Pragma("unroll")                                                      \
            for (int r = 0; r < 4; ++r) {                                          \
                const float pp = __builtin_amdgcn_exp2f(c[r]);                     \
                lp[n] += pp;                                                       \
                pv[r] = (bf16_t)pp;                                                \
            }                                                                      \
            pb[n] = as_s16x4(pv);                                                  \
        }                                                                          \
        __builtin_amdgcn_s_setprio(1);                                             \
        _Pragma("unroll")                                                          \
        for (int ds = 0; ds < 4; ++ds)                                             \
            _Pragma("unroll")                                                      \
            for (int n = 0; n < 4; ++n)                                            \
                o[ds][n] = __builtin_amdgcn_mfma_f32_16x16x16bf16_1k(               \
                    as_s16x4(va[ds]), pb[n], o[ds][n], 0, 0, 0);                   \
        __builtin_amdgcn_s_setprio(0);                                             \
        if (tt < 31) {                                                             \
            _Pragma("unroll")                                                      \
            for (int p = 0; p < 2; ++p) {                                          \
                const int row = srow + p * 32;                                     \
                *(bf16x8*)(&KSN[row * 72 + sc8]) = kreg[p];                        \
                *(bf16x8*)(&VSN[row * 72 + sc8]) = vreg[p];                        \
            }                                                                      \
        }                                                                          \
        __syncthreads();                                                           \
    } while (0)

    for (int t = 0; t < 32; t += 2) {
        ATTN_BODY(t,     Ks0, Vt0, Ks1, Vt1);
        ATTN_BODY(t + 1, Ks1, Vt1, Ks0, Vt0);
    }
#undef ATTN_BODY

    // ---- l reduction: over quads (shfl), then over waves (LDS) ----
#pragma unroll
    for (int n = 0; n < 4; ++n) {
        lp[n] += __shfl_xor(lp[n], 16);
        lp[n] += __shfl_xor(lp[n], 32);
    }
    if (quad == 0) {
#pragma unroll
        for (int n = 0; n < 4; ++n) Lred[w * 64 + n * 16 + m16] = lp[n];
    }
    __syncthreads();
    const float linv = 1.0f / (Lred[lane] + Lred[64 + lane] + Lred[128 + lane] + Lred[192 + lane]);

    // ---- O reduction: 4 phases; wave p owns dim-quarter p ----
    const size_t obase = (size_t)(b * SEQ + q0 + lane) * DIM_ + hh * HDIM;
#pragma unroll
    for (int p = 0; p < 4; ++p) {
        __syncthreads();
#pragma unroll
        for (int n = 0; n < 4; ++n)
#pragma unroll
            for (int r = 0; r < 4; ++r)
                Ored[w * 1040 + (quad * 4 + r) * 65 + n * 16 + m16] = o[p][n][r];
        __syncthreads();
        if (w == p) {
            union { bf16_t e[16]; bf16x8 v[2]; } ob;
#pragma unroll
            for (int d = 0; d < 16; ++d) {
                const float v = Ored[d * 65 + lane] + Ored[1040 + d * 65 + lane] +
                                Ored[2080 + d * 65 + lane] + Ored[3120 + d * 65 + lane];
                ob.e[d] = (bf16_t)(v * linv);
            }
            *(bf16x8*)(out + obase + p * 16)     = ob.v[0];
            *(bf16x8*)(out + obase + p * 16 + 8) = ob.v[1];
        }
    }
}

// ---------------------------------------------------------------------------
extern "C" void kernel_launch(void* const* d_in, const int* in_sizes, int n_in,
                              void* d_out, int out_size, void* d_ws, size_t ws_size,
                              hipStream_t stream) {
    const float* x     = (const float*)d_in[0];
    const float* w_qkv = (const float*)d_in[1];
    const float* w_out = (const float*)d_in[2];
    const float* b_out = (const float*)d_in[3];
    float* out = (float*)d_out;

    const int M = BATCH * SEQ;  // 4096

    bf16_t* qkv_b  = (bf16_t*)d_ws;                            // 4096x3072
    bf16_t* attn_b = qkv_b + (size_t)M * 3 * DIM_;             // 4096x1024
    bf16_t* vt_b   = attn_b + (size_t)M * DIM_;                // 32 heads x 64 x SEQ
    bf16_t* xb     = vt_b + (size_t)BATCH * NHEADS * HDIM * SEQ;
    bf16_t* wqkvb  = xb + (size_t)M * DIM_;
    bf16_t* woutb  = wqkvb + (size_t)3 * DIM_ * DIM_;

    // 0) cast x, w_qkv, w_out to bf16
    cast3<<<(XCNT + WQCNT + WOCNT) / (256 * 8), 256, 0, stream>>>(
        x, w_qkv, w_out, xb, wqkvb, woutb);

    // 1) qkv = x @ w_qkv^T  (q,k -> qkv_b; v -> vt_b transposed)
    gemm_lds<true><<<dim3(3 * DIM_ / 128, M / 128), 256, 0, stream>>>(
        xb, wqkvb, nullptr, qkv_b, vt_b, M, 3 * DIM_, DIM_);

    // 2) RoPE in place on q,k
    rope_bf16<<<(M * 2 * NHEADS) / 256, 256, 0, stream>>>(qkv_b);

    // 3) flash attention -> attn_b
    attn_mfma<<<dim3(SEQ / 64, BATCH * NHEADS), 256, 0, stream>>>(qkv_b, vt_b, attn_b);

    // 4) out = attn @ w_out^T + b_out (fp32), 128x64 tiles -> 512 blocks (2/CU)
    gemm_out64<<<dim3(DIM_ / 64, M / 128), 256, 0, stream>>>(
        attn_b, woutb, b_out, out, M, DIM_, DIM_);
}

// Round 7
// 213.443 us; speedup vs baseline: 1.1755x; 1.0103x over previous
//
#include <hip/hip_runtime.h>
#include <math.h>

typedef __bf16 bf16_t;
typedef bf16_t bf16x8 __attribute__((ext_vector_type(8)));
typedef bf16_t bf16x4 __attribute__((ext_vector_type(4)));
typedef short  s16x4  __attribute__((ext_vector_type(4)));
typedef float  f32x4  __attribute__((ext_vector_type(4)));

#define DIM_   1024
#define NHEADS 16
#define HDIM   64
#define SEQ    2048
#define BATCH  2

// log2(e)/8 : folded into q at RoPE time so attention softmax is exp2(s)
#define QK_SCALE 0.18033688011112042f

__device__ __forceinline__ s16x4 as_s16x4(bf16x4 v) {
    union { bf16x4 b; s16x4 s; } u; u.b = v; return u.s;
}

// async global->LDS, 16 B per lane; LDS dest = wave-uniform base + lane*16
__device__ __forceinline__ void gld16(const bf16_t* g, bf16_t* l) {
    __builtin_amdgcn_global_load_lds(
        (const __attribute__((address_space(1))) void*)g,
        (__attribute__((address_space(3))) void*)l, 16, 0, 0);
}

// ---------------------------------------------------------------------------
// Fused fp32->bf16 cast of x, w_qkv, w_out.
// ---------------------------------------------------------------------------
#define XCNT   (4096u * 1024u)
#define WQCNT  (3072u * 1024u)
#define WOCNT  (1024u * 1024u)
__global__ __launch_bounds__(256) void cast3(const float* __restrict__ s0,
                                             const float* __restrict__ s1,
                                             const float* __restrict__ s2,
                                             bf16_t* __restrict__ d0,
                                             bf16_t* __restrict__ d1,
                                             bf16_t* __restrict__ d2) {
    size_t i = ((size_t)blockIdx.x * 256 + threadIdx.x) * 8;
    const float* s; bf16_t* d; size_t off;
    if (i < XCNT)               { s = s0; d = d0; off = i; }
    else if (i < XCNT + WQCNT)  { s = s1; d = d1; off = i - XCNT; }
    else                        { s = s2; d = d2; off = i - XCNT - WQCNT; }
    float4 a = *(const float4*)(s + off);
    float4 b = *(const float4*)(s + off + 4);
    bf16x8 o = { (bf16_t)a.x, (bf16_t)a.y, (bf16_t)a.z, (bf16_t)a.w,
                 (bf16_t)b.x, (bf16_t)b.y, (bf16_t)b.z, (bf16_t)b.w };
    *(bf16x8*)(d + off) = o;
}

// ---------------------------------------------------------------------------
// m97-style bf16 GEMM: 128x128 tile, BK=32, global_load_lds width-16 staging,
// unpadded LDS, b128 frag reads. Used for the QKV GEMM (768 blocks = 3/CU).
// ---------------------------------------------------------------------------
template <bool QKV>
__global__ __launch_bounds__(256) void gemm_lds(const bf16_t* __restrict__ A,
                                                const bf16_t* __restrict__ B,
                                                const float* __restrict__ bias,
                                                void* __restrict__ Cout,
                                                bf16_t* __restrict__ vt,
                                                int M, int N, int K) {
    __shared__ __align__(16) bf16_t As[128 * 32];
    __shared__ __align__(16) bf16_t Bs[128 * 32];
    const int tid  = threadIdx.x;
    const int m0   = blockIdx.y * 128;
    const int n0   = blockIdx.x * 128;
    const int w    = tid >> 6;
    const int lane = tid & 63;
    const int m16  = lane & 15;
    const int quad = lane >> 4;
    const int wm   = (w >> 1) * 64;
    const int wn   = (w & 1) * 64;
    const int lrow = lane >> 2;
    const int lcol = (lane & 3) * 8;

    const bf16_t* pa0 = A + (size_t)(m0 + w * 16 + lrow) * K + lcol;
    const bf16_t* pb0 = B + (size_t)(n0 + w * 16 + lrow) * K + lcol;
    bf16_t* lA0 = &As[(w * 16) * 32];
    bf16_t* lA1 = &As[(64 + w * 16) * 32];
    bf16_t* lB0 = &Bs[(w * 16) * 32];
    bf16_t* lB1 = &Bs[(64 + w * 16) * 32];

    f32x4 acc[4][4] = {};

    for (int k0 = 0; k0 < K; k0 += 32) {
        __syncthreads();
        gld16(pa0 + k0, lA0);
        gld16(pa0 + (size_t)64 * K + k0, lA1);
        gld16(pb0 + k0, lB0);
        gld16(pb0 + (size_t)64 * K + k0, lB1);
        __syncthreads();

        bf16x8 af[4], bfr[4];
#pragma unroll
        for (int i = 0; i < 4; ++i)
            af[i] = *(const bf16x8*)(&As[(wm + i * 16 + m16) * 32 + quad * 8]);
#pragma unroll
        for (int j = 0; j < 4; ++j)
            bfr[j] = *(const bf16x8*)(&Bs[(wn + j * 16 + m16) * 32 + quad * 8]);
#pragma unroll
        for (int i = 0; i < 4; ++i)
#pragma unroll
            for (int j = 0; j < 4; ++j)
                acc[i][j] = __builtin_amdgcn_mfma_f32_16x16x32_bf16(af[i], bfr[j], acc[i][j], 0, 0, 0);
    }

    if (QKV && n0 >= 2 * DIM_) {
        const int b      = m0 >> 11;
        const int s_base = (m0 & (SEQ - 1)) + wm;
#pragma unroll
        for (int j = 0; j < 4; ++j) {
            const int cit = wn + j * 16 + m16;
            const int h   = ((n0 - 2 * DIM_) >> 6) + (cit >> 6);
            const int d   = cit & 63;
            bf16_t* vrow = vt + ((size_t)(b * 16 + h) * 64 + d) * SEQ + s_base;
#pragma unroll
            for (int i = 0; i < 4; ++i) {
                bf16x4 ov = { (bf16_t)acc[i][j][0], (bf16_t)acc[i][j][1],
                              (bf16_t)acc[i][j][2], (bf16_t)acc[i][j][3] };
                *(bf16x4*)(vrow + i * 16 + quad * 4) = ov;
            }
        }
    } else if (QKV) {
        bf16_t* C = (bf16_t*)Cout;
#pragma unroll
        for (int i = 0; i < 4; ++i)
#pragma unroll
            for (int j = 0; j < 4; ++j) {
                const int col = n0 + wn + j * 16 + m16;
#pragma unroll
                for (int r = 0; r < 4; ++r)
                    C[(size_t)(m0 + wm + i * 16 + quad * 4 + r) * N + col] = (bf16_t)acc[i][j][r];
            }
    } else {
        float* C = (float*)Cout;
#pragma unroll
        for (int j = 0; j < 4; ++j) {
            const int col = n0 + wn + j * 16 + m16;
            const float bv = bias[col];
#pragma unroll
            for (int i = 0; i < 4; ++i)
#pragma unroll
                for (int r = 0; r < 4; ++r)
                    C[(size_t)(m0 + wm + i * 16 + quad * 4 + r) * N + col] = acc[i][j][r] + bv;
        }
    }
}

// ---------------------------------------------------------------------------
// Output GEMM, 128x64 tile (R5: 512 blocks = 2/CU, small win — keep).
// ---------------------------------------------------------------------------
__global__ __launch_bounds__(256) void gemm_out64(const bf16_t* __restrict__ A,
                                                  const bf16_t* __restrict__ B,
                                                  const float* __restrict__ bias,
                                                  float* __restrict__ C,
                                                  int M, int N, int K) {
    __shared__ __align__(16) bf16_t As[128 * 32];
    __shared__ __align__(16) bf16_t Bs[64 * 32];
    const int tid  = threadIdx.x;
    const int m0   = blockIdx.y * 128;
    const int n0   = blockIdx.x * 64;
    const int w    = tid >> 6;
    const int lane = tid & 63;
    const int m16  = lane & 15;
    const int quad = lane >> 4;
    const int wm   = (w >> 1) * 64;
    const int wn   = (w & 1) * 32;
    const int lrow = lane >> 2;
    const int lcol = (lane & 3) * 8;

    const bf16_t* pa0 = A + (size_t)(m0 + w * 16 + lrow) * K + lcol;
    const bf16_t* pb0 = B + (size_t)(n0 + w * 16 + lrow) * K + lcol;
    bf16_t* lA0 = &As[(w * 16) * 32];
    bf16_t* lA1 = &As[(64 + w * 16) * 32];
    bf16_t* lB0 = &Bs[(w * 16) * 32];

    f32x4 acc[4][2] = {};

    for (int k0 = 0; k0 < K; k0 += 32) {
        __syncthreads();
        gld16(pa0 + k0, lA0);
        gld16(pa0 + (size_t)64 * K + k0, lA1);
        gld16(pb0 + k0, lB0);
        __syncthreads();

        bf16x8 af[4], bfr[2];
#pragma unroll
        for (int i = 0; i < 4; ++i)
            af[i] = *(const bf16x8*)(&As[(wm + i * 16 + m16) * 32 + quad * 8]);
#pragma unroll
        for (int j = 0; j < 2; ++j)
            bfr[j] = *(const bf16x8*)(&Bs[(wn + j * 16 + m16) * 32 + quad * 8]);
#pragma unroll
        for (int i = 0; i < 4; ++i)
#pragma unroll
            for (int j = 0; j < 2; ++j)
                acc[i][j] = __builtin_amdgcn_mfma_f32_16x16x32_bf16(af[i], bfr[j], acc[i][j], 0, 0, 0);
    }

#pragma unroll
    for (int j = 0; j < 2; ++j) {
        const int col = n0 + wn + j * 16 + m16;
        const float bv = bias[col];
#pragma unroll
        for (int i = 0; i < 4; ++i)
#pragma unroll
            for (int r = 0; r < 4; ++r)
                C[(size_t)(m0 + wm + i * 16 + quad * 4 + r) * N + col] = acc[i][j][r] + bv;
    }
}

// ---------------------------------------------------------------------------
// RoPE in place on bf16 qkv (q and k thirds). q scaled by QK_SCALE.
// ---------------------------------------------------------------------------
__global__ __launch_bounds__(256) void rope_bf16(bf16_t* __restrict__ qkv) {
    __shared__ float ctab[8][32];
    __shared__ float stab[8][32];
    const int tid = threadIdx.x;
    const int sl  = tid >> 5, j = tid & 31;
    const int s   = (int)((blockIdx.x * 8 + sl) & (SEQ - 1));
    const float freq = exp2f(-0.41524101186092029f * (float)j);  // 10000^(-j/32)
    float sn, cs;
    sincosf((float)s * freq, &sn, &cs);
    ctab[sl][j] = cs;
    stab[sl][j] = sn;
    __syncthreads();

    const int gid   = blockIdx.x * 256 + tid;
    const int m     = gid >> 5;
    const int rr    = gid & 31;
    const int which = rr >> 4;
    const int hh    = rr & 15;
    const float osc = (which == 0) ? QK_SCALE : 1.0f;

    bf16_t* p = qkv + (size_t)m * (3 * DIM_) + which * DIM_ + hh * HDIM;
    union { bf16_t e[64]; bf16x8 v[8]; } X, O;
#pragma unroll
    for (int i = 0; i < 8; ++i) X.v[i] = *(const bf16x8*)(p + i * 8);
#pragma unroll
    for (int t = 0; t < 32; ++t) {
        const float x1 = (float)X.e[2 * t];
        const float x2 = (float)X.e[2 * t + 1];
        const float c  = ctab[sl][t];
        const float s2 = stab[sl][t];
        O.e[t]      = (bf16_t)((x1 * c - x2 * s2) * osc);
        O.e[32 + t] = (bf16_t)((x1 * s2 + x2 * c) * osc);
    }
#pragma unroll
    for (int i = 0; i < 8; ++i) *(bf16x8*)(p + i * 8) = O.v[i];
}

// ---------------------------------------------------------------------------
// Flash attention, key-split waves. R6 structure (LDS double-buffer, ONE
// barrier/tile) + R7: (a) pointer-increment staging addresses (no per-tile
// 64-bit muls), (b) parallel O-reduction epilogue (all 4 waves sum+store
// per phase instead of one).
// ---------------------------------------------------------------------------
__global__ __launch_bounds__(256) void attn_mfma(const bf16_t* __restrict__ qkv,
                                                 const bf16_t* __restrict__ vt,
                                                 bf16_t* __restrict__ out) {
    __shared__ __align__(16) char smem[37888];
    bf16_t* Ks0  = (bf16_t*)smem;              // 64 x 72 bf16 (9216 B)
    bf16_t* Vt0  = (bf16_t*)(smem + 9216);
    bf16_t* Ks1  = (bf16_t*)(smem + 18432);
    bf16_t* Vt1  = (bf16_t*)(smem + 27648);
    float*  Ored = (float*)smem;               // epilogue alias: 16640 B
    float*  Lred = (float*)(smem + 36864);     // 1024 B

    const int tid  = threadIdx.x;
    const int w    = tid >> 6;
    const int lane = tid & 63;
    const int m16  = lane & 15;
    const int quad = lane >> 4;
    const int bh   = blockIdx.y;
    const int b    = bh >> 4;
    const int hh   = bh & 15;
    const int q0   = blockIdx.x * 64;

    const size_t rs = 3 * DIM_;
    const bf16_t* qbase = qkv + (size_t)(b * SEQ) * rs + hh * HDIM;
    const bf16_t* kbase = qbase + DIM_;
    const bf16_t* vtg   = vt + (size_t)bh * 64 * SEQ;

    // Q fragments: qf[n][kt] = Q[q0+n*16+m16][kt*32+quad*8 ..+7]
    bf16x8 qf[4][2];
#pragma unroll
    for (int n = 0; n < 4; ++n)
#pragma unroll
        for (int kt = 0; kt < 2; ++kt)
            qf[n][kt] = *(const bf16x8*)(qbase + (size_t)(q0 + n * 16 + m16) * rs + kt * 32 + quad * 8);

    f32x4 o[4][4] = {};  // o[ds][n]: partial O^T over this wave's keys
    float lp[4] = {};    // per-lane partial l for q = n*16+m16

    // coalesced staging geometry: 256 threads cover 32 rows/pass
    const int srow = tid >> 3;          // 0..31
    const int sc8  = (tid & 7) * 8;     // 0..56

    bf16x8 kreg[2], vreg[2];

    // prologue: tile 0 -> regs -> buf0 -> barrier
#pragma unroll
    for (int p = 0; p < 2; ++p) {
        const int row = srow + p * 32;
        kreg[p] = *(const bf16x8*)(kbase + (size_t)row * rs + sc8);
        vreg[p] = *(const bf16x8*)(vtg + (size_t)row * SEQ + sc8);
    }
#pragma unroll
    for (int p = 0; p < 2; ++p) {
        const int row = srow + p * 32;
        *(bf16x8*)(&Ks0[row * 72 + sc8]) = kreg[p];
        *(bf16x8*)(&Vt0[row * 72 + sc8]) = vreg[p];
    }
    __syncthreads();

    // persistent prefetch pointers (tile 1 rows), advanced by one tile/body
    const bf16_t* kg0 = kbase + (size_t)(64 + srow) * rs + sc8;
    const bf16_t* kg1 = kg0 + (size_t)32 * rs;
    const bf16_t* vg0 = vtg + (size_t)srow * SEQ + 64 + sc8;
    const bf16_t* vg1 = vg0 + (size_t)32 * SEQ;
    const size_t kadv = (size_t)64 * rs;

    // body(T): compute from KS/VS; prefetch T+1 to regs; write regs -> KSN/VSN
#define ATTN_BODY(T, KS, VS, KSN, VSN)                                             \
    do {                                                                           \
        const int tt = (T);                                                        \
        if (tt < 31) {                                                             \
            kreg[0] = *(const bf16x8*)(kg0);                                       \
            kreg[1] = *(const bf16x8*)(kg1);                                       \
            vreg[0] = *(const bf16x8*)(vg0);                                       \
            vreg[1] = *(const bf16x8*)(vg1);                                       \
            kg0 += kadv; kg1 += kadv; vg0 += 64; vg1 += 64;                        \
        }                                                                          \
        bf16x8 ak0 = *(const bf16x8*)(&KS[(w * 16 + m16) * 72 + 0 * 32 + quad * 8]); \
        bf16x8 ak1 = *(const bf16x8*)(&KS[(w * 16 + m16) * 72 + 1 * 32 + quad * 8]); \
        bf16x4 va[4];                                                              \
        _Pragma("unroll")                                                          \
        for (int ds = 0; ds < 4; ++ds)                                             \
            va[ds] = *(const bf16x4*)(&VS[(ds * 16 + m16) * 72 + w * 16 + quad * 4]); \
        s16x4 pb[4];                                                               \
        _Pragma("unroll")                                                          \
        for (int n = 0; n < 4; ++n) {                                              \
            f32x4 c = {};                                                          \
            c = __builtin_amdgcn_mfma_f32_16x16x32_bf16(ak0, qf[n][0], c, 0, 0, 0); \
            c = __builtin_amdgcn_mfma_f32_16x16x32_bf16(ak1, qf[n][1], c, 0, 0, 0); \
            bf16x4 pv;                                                             \
            _Pragma("unroll")                                                      \
            for (int r = 0; r < 4; ++r) {                                          \
                const float pp = __builtin_amdgcn_exp2f(c[r]);                     \
                lp[n] += pp;                                                       \
                pv[r] = (bf16_t)pp;                                                \
            }                                                                      \
            pb[n] = as_s16x4(pv);                                                  \
        }                                                                          \
        __builtin_amdgcn_s_setprio(1);                                             \
        _Pragma("unroll")                                                          \
        for (int ds = 0; ds < 4; ++ds)                                             \
            _Pragma("unroll")                                                      \
            for (int n = 0; n < 4; ++n)                                            \
                o[ds][n] = __builtin_amdgcn_mfma_f32_16x16x16bf16_1k(               \
                    as_s16x4(va[ds]), pb[n], o[ds][n], 0, 0, 0);                   \
        __builtin_amdgcn_s_setprio(0);                                             \
        if (tt < 31) {                                                             \
            _Pragma("unroll")                                                      \
            for (int p = 0; p < 2; ++p) {                                          \
                const int row = srow + p * 32;                                     \
                *(bf16x8*)(&KSN[row * 72 + sc8]) = kreg[p];                        \
                *(bf16x8*)(&VSN[row * 72 + sc8]) = vreg[p];                        \
            }                                                                      \
        }                                                                          \
        __syncthreads();                                                           \
    } while (0)

    for (int t = 0; t < 32; t += 2) {
        ATTN_BODY(t,     Ks0, Vt0, Ks1, Vt1);
        ATTN_BODY(t + 1, Ks1, Vt1, Ks0, Vt0);
    }
#undef ATTN_BODY

    // ---- l reduction: over quads (shfl), then over waves (LDS) ----
#pragma unroll
    for (int n = 0; n < 4; ++n) {
        lp[n] += __shfl_xor(lp[n], 16);
        lp[n] += __shfl_xor(lp[n], 32);
    }
    if (quad == 0) {
#pragma unroll
        for (int n = 0; n < 4; ++n) Lred[w * 64 + n * 16 + m16] = lp[n];
    }
    __syncthreads();
    const float linv = 1.0f / (Lred[lane] + Lred[64 + lane] + Lred[128 + lane] + Lred[192 + lane]);

    // ---- O reduction: 4 phases; ALL waves sum+store (wave w owns dims
    // [w*4, w*4+4) of the phase's 16-dim slab; lane = query) ----
    const size_t obase = (size_t)(b * SEQ + q0 + lane) * DIM_ + hh * HDIM;
#pragma unroll
    for (int p = 0; p < 4; ++p) {
        __syncthreads();
#pragma unroll
        for (int n = 0; n < 4; ++n)
#pragma unroll
            for (int r = 0; r < 4; ++r)
                Ored[w * 1040 + (quad * 4 + r) * 65 + n * 16 + m16] = o[p][n][r];
        __syncthreads();
        union { bf16_t e[4]; bf16x4 v; } ob;
#pragma unroll
        for (int d = 0; d < 4; ++d) {
            const int dd = w * 4 + d;
            const float v = Ored[dd * 65 + lane] + Ored[1040 + dd * 65 + lane] +
                            Ored[2080 + dd * 65 + lane] + Ored[3120 + dd * 65 + lane];
            ob.e[d] = (bf16_t)(v * linv);
        }
        *(bf16x4*)(out + obase + p * 16 + w * 4) = ob.v;
    }
}

// ---------------------------------------------------------------------------
extern "C" void kernel_launch(void* const* d_in, const int* in_sizes, int n_in,
                              void* d_out, int out_size, void* d_ws, size_t ws_size,
                              hipStream_t stream) {
    const float* x     = (const float*)d_in[0];
    const float* w_qkv = (const float*)d_in[1];
    const float* w_out = (const float*)d_in[2];
    const float* b_out = (const float*)d_in[3];
    float* out = (float*)d_out;

    const int M = BATCH * SEQ;  // 4096

    bf16_t* qkv_b  = (bf16_t*)d_ws;                            // 4096x3072
    bf16_t* attn_b = qkv_b + (size_t)M * 3 * DIM_;             // 4096x1024
    bf16_t* vt_b   = attn_b + (size_t)M * DIM_;                // 32 heads x 64 x SEQ
    bf16_t* xb     = vt_b + (size_t)BATCH * NHEADS * HDIM * SEQ;
    bf16_t* wqkvb  = xb + (size_t)M * DIM_;
    bf16_t* woutb  = wqkvb + (size_t)3 * DIM_ * DIM_;

    // 0) cast x, w_qkv, w_out to bf16
    cast3<<<(XCNT + WQCNT + WOCNT) / (256 * 8), 256, 0, stream>>>(
        x, w_qkv, w_out, xb, wqkvb, woutb);

    // 1) qkv = x @ w_qkv^T  (q,k -> qkv_b; v -> vt_b transposed)
    gemm_lds<true><<<dim3(3 * DIM_ / 128, M / 128), 256, 0, stream>>>(
        xb, wqkvb, nullptr, qkv_b, vt_b, M, 3 * DIM_, DIM_);

    // 2) RoPE in place on q,k
    rope_bf16<<<(M * 2 * NHEADS) / 256, 256, 0, stream>>>(qkv_b);

    // 3) flash attention -> attn_b
    attn_mfma<<<dim3(SEQ / 64, BATCH * NHEADS), 256, 0, stream>>>(qkv_b, vt_b, attn_b);

    // 4) out = attn @ w_out^T + b_out (fp32), 128x64 tiles -> 512 blocks (2/CU)
    gemm_out64<<<dim3(DIM_ / 64, M / 128), 256, 0, stream>>>(
        attn_b, woutb, b_out, out, M, DIM_, DIM_);
}

// Round 8
// 206.835 us; speedup vs baseline: 1.2131x; 1.0320x over previous
//
#include <hip/hip_runtime.h>
#include <math.h>

typedef __bf16 bf16_t;
typedef bf16_t bf16x8 __attribute__((ext_vector_type(8)));
typedef bf16_t bf16x4 __attribute__((ext_vector_type(4)));
typedef short  s16x4  __attribute__((ext_vector_type(4)));
typedef float  f32x4  __attribute__((ext_vector_type(4)));

#define DIM_   1024
#define NHEADS 16
#define HDIM   64
#define SEQ    2048
#define BATCH  2

// log2(e)/8 : folded into q at RoPE time so attention softmax is exp2(s)
#define QK_SCALE 0.18033688011112042f

__device__ __forceinline__ s16x4 as_s16x4(bf16x4 v) {
    union { bf16x4 b; s16x4 s; } u; u.b = v; return u.s;
}

// async global->LDS, 16 B per lane; LDS dest = wave-uniform base + lane*16
__device__ __forceinline__ void gld16(const bf16_t* g, bf16_t* l) {
    __builtin_amdgcn_global_load_lds(
        (const __attribute__((address_space(1))) void*)g,
        (__attribute__((address_space(3))) void*)l, 16, 0, 0);
}

// ---------------------------------------------------------------------------
// Fused fp32->bf16 cast of x, w_qkv, w_out.
// ---------------------------------------------------------------------------
#define XCNT   (4096u * 1024u)
#define WQCNT  (3072u * 1024u)
#define WOCNT  (1024u * 1024u)
__global__ __launch_bounds__(256) void cast3(const float* __restrict__ s0,
                                             const float* __restrict__ s1,
                                             const float* __restrict__ s2,
                                             bf16_t* __restrict__ d0,
                                             bf16_t* __restrict__ d1,
                                             bf16_t* __restrict__ d2) {
    size_t i = ((size_t)blockIdx.x * 256 + threadIdx.x) * 8;
    const float* s; bf16_t* d; size_t off;
    if (i < XCNT)               { s = s0; d = d0; off = i; }
    else if (i < XCNT + WQCNT)  { s = s1; d = d1; off = i - XCNT; }
    else                        { s = s2; d = d2; off = i - XCNT - WQCNT; }
    float4 a = *(const float4*)(s + off);
    float4 b = *(const float4*)(s + off + 4);
    bf16x8 o = { (bf16_t)a.x, (bf16_t)a.y, (bf16_t)a.z, (bf16_t)a.w,
                 (bf16_t)b.x, (bf16_t)b.y, (bf16_t)b.z, (bf16_t)b.w };
    *(bf16x8*)(d + off) = o;
}

// ---------------------------------------------------------------------------
// bf16 GEMM, 128x128 tile, BK=32. R8: LDS DOUBLE-BUFFER 2-PHASE — stage tile
// k+1 into buf^1 BEFORE computing tile k from buf, ONE barrier per K-step.
// The compiler's vmcnt(0)-before-barrier then lands after the MFMA cluster,
// so staging loads overlap compute (old drain-style exposed ~500cyc/step).
// ---------------------------------------------------------------------------
template <bool QKV>
__global__ __launch_bounds__(256) void gemm_lds(const bf16_t* __restrict__ A,
                                                const bf16_t* __restrict__ B,
                                                const float* __restrict__ bias,
                                                void* __restrict__ Cout,
                                                bf16_t* __restrict__ vt,
                                                int M, int N, int K) {
    __shared__ __align__(16) bf16_t As[2][128 * 32];
    __shared__ __align__(16) bf16_t Bs[2][128 * 32];
    const int tid  = threadIdx.x;
    const int m0   = blockIdx.y * 128;
    const int n0   = blockIdx.x * 128;
    const int w    = tid >> 6;
    const int lane = tid & 63;
    const int m16  = lane & 15;
    const int quad = lane >> 4;
    const int wm   = (w >> 1) * 64;
    const int wn   = (w & 1) * 64;
    const int lrow = lane >> 2;
    const int lcol = (lane & 3) * 8;

    const bf16_t* pa0 = A + (size_t)(m0 + w * 16 + lrow) * K + lcol;
    const bf16_t* pb0 = B + (size_t)(n0 + w * 16 + lrow) * K + lcol;
    const int sOffA0 = (w * 16) * 32;
    const int sOffA1 = (64 + w * 16) * 32;

    // prologue: stage k=0 into buffer 0
    gld16(pa0, (bf16_t*)As + sOffA0);
    gld16(pa0 + (size_t)64 * K, (bf16_t*)As + sOffA1);
    gld16(pb0, (bf16_t*)Bs + sOffA0);
    gld16(pb0 + (size_t)64 * K, (bf16_t*)Bs + sOffA1);
    __syncthreads();

    f32x4 acc[4][4] = {};
    int buf = 0;

    for (int k0 = 0; k0 < K; k0 += 32) {
        const int nb = buf ^ 1;
        if (k0 + 32 < K) {  // stage next tile into the other buffer
            gld16(pa0 + k0 + 32, (bf16_t*)As + nb * 4096 + sOffA0);
            gld16(pa0 + (size_t)64 * K + k0 + 32, (bf16_t*)As + nb * 4096 + sOffA1);
            gld16(pb0 + k0 + 32, (bf16_t*)Bs + nb * 4096 + sOffA0);
            gld16(pb0 + (size_t)64 * K + k0 + 32, (bf16_t*)Bs + nb * 4096 + sOffA1);
        }
        const bf16_t* sA = (const bf16_t*)As + buf * 4096;
        const bf16_t* sB = (const bf16_t*)Bs + buf * 4096;
        bf16x8 af[4], bfr[4];
#pragma unroll
        for (int i = 0; i < 4; ++i)
            af[i] = *(const bf16x8*)(sA + (wm + i * 16 + m16) * 32 + quad * 8);
#pragma unroll
        for (int j = 0; j < 4; ++j)
            bfr[j] = *(const bf16x8*)(sB + (wn + j * 16 + m16) * 32 + quad * 8);
#pragma unroll
        for (int i = 0; i < 4; ++i)
#pragma unroll
            for (int j = 0; j < 4; ++j)
                acc[i][j] = __builtin_amdgcn_mfma_f32_16x16x32_bf16(af[i], bfr[j], acc[i][j], 0, 0, 0);
        __syncthreads();   // vmcnt(0) drain lands here, AFTER compute
        buf = nb;
    }

    if (QKV && n0 >= 2 * DIM_) {
        const int b      = m0 >> 11;
        const int s_base = (m0 & (SEQ - 1)) + wm;
#pragma unroll
        for (int j = 0; j < 4; ++j) {
            const int cit = wn + j * 16 + m16;
            const int h   = ((n0 - 2 * DIM_) >> 6) + (cit >> 6);
            const int d   = cit & 63;
            bf16_t* vrow = vt + ((size_t)(b * 16 + h) * 64 + d) * SEQ + s_base;
#pragma unroll
            for (int i = 0; i < 4; ++i) {
                bf16x4 ov = { (bf16_t)acc[i][j][0], (bf16_t)acc[i][j][1],
                              (bf16_t)acc[i][j][2], (bf16_t)acc[i][j][3] };
                *(bf16x4*)(vrow + i * 16 + quad * 4) = ov;
            }
        }
    } else if (QKV) {
        bf16_t* C = (bf16_t*)Cout;
#pragma unroll
        for (int i = 0; i < 4; ++i)
#pragma unroll
            for (int j = 0; j < 4; ++j) {
                const int col = n0 + wn + j * 16 + m16;
#pragma unroll
                for (int r = 0; r < 4; ++r)
                    C[(size_t)(m0 + wm + i * 16 + quad * 4 + r) * N + col] = (bf16_t)acc[i][j][r];
            }
    } else {
        float* C = (float*)Cout;
#pragma unroll
        for (int j = 0; j < 4; ++j) {
            const int col = n0 + wn + j * 16 + m16;
            const float bv = bias[col];
#pragma unroll
            for (int i = 0; i < 4; ++i)
#pragma unroll
                for (int r = 0; r < 4; ++r)
                    C[(size_t)(m0 + wm + i * 16 + quad * 4 + r) * N + col] = acc[i][j][r] + bv;
        }
    }
}

// ---------------------------------------------------------------------------
// Output GEMM, 128x64 tile, same R8 double-buffer 2-phase transformation.
// ---------------------------------------------------------------------------
__global__ __launch_bounds__(256) void gemm_out64(const bf16_t* __restrict__ A,
                                                  const bf16_t* __restrict__ B,
                                                  const float* __restrict__ bias,
                                                  float* __restrict__ C,
                                                  int M, int N, int K) {
    __shared__ __align__(16) bf16_t As[2][128 * 32];
    __shared__ __align__(16) bf16_t Bs[2][64 * 32];
    const int tid  = threadIdx.x;
    const int m0   = blockIdx.y * 128;
    const int n0   = blockIdx.x * 64;
    const int w    = tid >> 6;
    const int lane = tid & 63;
    const int m16  = lane & 15;
    const int quad = lane >> 4;
    const int wm   = (w >> 1) * 64;
    const int wn   = (w & 1) * 32;
    const int lrow = lane >> 2;
    const int lcol = (lane & 3) * 8;

    const bf16_t* pa0 = A + (size_t)(m0 + w * 16 + lrow) * K + lcol;
    const bf16_t* pb0 = B + (size_t)(n0 + w * 16 + lrow) * K + lcol;
    const int sOff0 = (w * 16) * 32;
    const int sOff1 = (64 + w * 16) * 32;

    // prologue: stage k=0 into buffer 0
    gld16(pa0, (bf16_t*)As + sOff0);
    gld16(pa0 + (size_t)64 * K, (bf16_t*)As + sOff1);
    gld16(pb0, (bf16_t*)Bs + sOff0);
    __syncthreads();

    f32x4 acc[4][2] = {};
    int buf = 0;

    for (int k0 = 0; k0 < K; k0 += 32) {
        const int nb = buf ^ 1;
        if (k0 + 32 < K) {
            gld16(pa0 + k0 + 32, (bf16_t*)As + nb * 4096 + sOff0);
            gld16(pa0 + (size_t)64 * K + k0 + 32, (bf16_t*)As + nb * 4096 + sOff1);
            gld16(pb0 + k0 + 32, (bf16_t*)Bs + nb * 2048 + sOff0);
        }
        const bf16_t* sA = (const bf16_t*)As + buf * 4096;
        const bf16_t* sB = (const bf16_t*)Bs + buf * 2048;
        bf16x8 af[4], bfr[2];
#pragma unroll
        for (int i = 0; i < 4; ++i)
            af[i] = *(const bf16x8*)(sA + (wm + i * 16 + m16) * 32 + quad * 8);
#pragma unroll
        for (int j = 0; j < 2; ++j)
            bfr[j] = *(const bf16x8*)(sB + (wn + j * 16 + m16) * 32 + quad * 8);
#pragma unroll
        for (int i = 0; i < 4; ++i)
#pragma unroll
            for (int j = 0; j < 2; ++j)
                acc[i][j] = __builtin_amdgcn_mfma_f32_16x16x32_bf16(af[i], bfr[j], acc[i][j], 0, 0, 0);
        __syncthreads();
        buf = nb;
    }

#pragma unroll
    for (int j = 0; j < 2; ++j) {
        const int col = n0 + wn + j * 16 + m16;
        const float bv = bias[col];
#pragma unroll
        for (int i = 0; i < 4; ++i)
#pragma unroll
            for (int r = 0; r < 4; ++r)
                C[(size_t)(m0 + wm + i * 16 + quad * 4 + r) * N + col] = acc[i][j][r] + bv;
    }
}

// ---------------------------------------------------------------------------
// RoPE in place on bf16 qkv (q and k thirds). q scaled by QK_SCALE.
// ---------------------------------------------------------------------------
__global__ __launch_bounds__(256) void rope_bf16(bf16_t* __restrict__ qkv) {
    __shared__ float ctab[8][32];
    __shared__ float stab[8][32];
    const int tid = threadIdx.x;
    const int sl  = tid >> 5, j = tid & 31;
    const int s   = (int)((blockIdx.x * 8 + sl) & (SEQ - 1));
    const float freq = exp2f(-0.41524101186092029f * (float)j);  // 10000^(-j/32)
    float sn, cs;
    sincosf((float)s * freq, &sn, &cs);
    ctab[sl][j] = cs;
    stab[sl][j] = sn;
    __syncthreads();

    const int gid   = blockIdx.x * 256 + tid;
    const int m     = gid >> 5;
    const int rr    = gid & 31;
    const int which = rr >> 4;
    const int hh    = rr & 15;
    const float osc = (which == 0) ? QK_SCALE : 1.0f;

    bf16_t* p = qkv + (size_t)m * (3 * DIM_) + which * DIM_ + hh * HDIM;
    union { bf16_t e[64]; bf16x8 v[8]; } X, O;
#pragma unroll
    for (int i = 0; i < 8; ++i) X.v[i] = *(const bf16x8*)(p + i * 8);
#pragma unroll
    for (int t = 0; t < 32; ++t) {
        const float x1 = (float)X.e[2 * t];
        const float x2 = (float)X.e[2 * t + 1];
        const float c  = ctab[sl][t];
        const float s2 = stab[sl][t];
        O.e[t]      = (bf16_t)((x1 * c - x2 * s2) * osc);
        O.e[32 + t] = (bf16_t)((x1 * s2 + x2 * c) * osc);
    }
#pragma unroll
    for (int i = 0; i < 8; ++i) *(bf16x8*)(p + i * 8) = O.v[i];
}

// ---------------------------------------------------------------------------
// Flash attention, key-split waves. R7 structure (unchanged): LDS dbuf, one
// barrier/tile, pointer-increment staging, parallel epilogue.
// ---------------------------------------------------------------------------
__global__ __launch_bounds__(256) void attn_mfma(const bf16_t* __restrict__ qkv,
                                                 const bf16_t* __restrict__ vt,
                                                 bf16_t* __restrict__ out) {
    __shared__ __align__(16) char smem[37888];
    bf16_t* Ks0  = (bf16_t*)smem;              // 64 x 72 bf16 (9216 B)
    bf16_t* Vt0  = (bf16_t*)(smem + 9216);
    bf16_t* Ks1  = (bf16_t*)(smem + 18432);
    bf16_t* Vt1  = (bf16_t*)(smem + 27648);
    float*  Ored = (float*)smem;               // epilogue alias: 16640 B
    float*  Lred = (float*)(smem + 36864);     // 1024 B

    const int tid  = threadIdx.x;
    const int w    = tid >> 6;
    const int lane = tid & 63;
    const int m16  = lane & 15;
    const int quad = lane >> 4;
    const int bh   = blockIdx.y;
    const int b    = bh >> 4;
    const int hh   = bh & 15;
    const int q0   = blockIdx.x * 64;

    const size_t rs = 3 * DIM_;
    const bf16_t* qbase = qkv + (size_t)(b * SEQ) * rs + hh * HDIM;
    const bf16_t* kbase = qbase + DIM_;
    const bf16_t* vtg   = vt + (size_t)bh * 64 * SEQ;

    // Q fragments: qf[n][kt] = Q[q0+n*16+m16][kt*32+quad*8 ..+7]
    bf16x8 qf[4][2];
#pragma unroll
    for (int n = 0; n < 4; ++n)
#pragma unroll
        for (int kt = 0; kt < 2; ++kt)
            qf[n][kt] = *(const bf16x8*)(qbase + (size_t)(q0 + n * 16 + m16) * rs + kt * 32 + quad * 8);

    f32x4 o[4][4] = {};  // o[ds][n]: partial O^T over this wave's keys
    float lp[4] = {};    // per-lane partial l for q = n*16+m16

    // coalesced staging geometry: 256 threads cover 32 rows/pass
    const int srow = tid >> 3;          // 0..31
    const int sc8  = (tid & 7) * 8;     // 0..56

    bf16x8 kreg[2], vreg[2];

    // prologue: tile 0 -> regs -> buf0 -> barrier
#pragma unroll
    for (int p = 0; p < 2; ++p) {
        const int row = srow + p * 32;
        kreg[p] = *(const bf16x8*)(kbase + (size_t)row * rs + sc8);
        vreg[p] = *(const bf16x8*)(vtg + (size_t)row * SEQ + sc8);
    }
#pragma unroll
    for (int p = 0; p < 2; ++p) {
        const int row = srow + p * 32;
        *(bf16x8*)(&Ks0[row * 72 + sc8]) = kreg[p];
        *(bf16x8*)(&Vt0[row * 72 + sc8]) = vreg[p];
    }
    __syncthreads();

    // persistent prefetch pointers (tile 1 rows), advanced by one tile/body
    const bf16_t* kg0 = kbase + (size_t)(64 + srow) * rs + sc8;
    const bf16_t* kg1 = kg0 + (size_t)32 * rs;
    const bf16_t* vg0 = vtg + (size_t)srow * SEQ + 64 + sc8;
    const bf16_t* vg1 = vg0 + (size_t)32 * SEQ;
    const size_t kadv = (size_t)64 * rs;

    // body(T): compute from KS/VS; prefetch T+1 to regs; write regs -> KSN/VSN
#define ATTN_BODY(T, KS, VS, KSN, VSN)                                             \
    do {                                                                           \
        const int tt = (T);                                                        \
        if (tt < 31) {                                                             \
            kreg[0] = *(const bf16x8*)(kg0);                                       \
            kreg[1] = *(const bf16x8*)(kg1);                                       \
            vreg[0] = *(const bf16x8*)(vg0);                                       \
            vreg[1] = *(const bf16x8*)(vg1);                                       \
            kg0 += kadv; kg1 += kadv; vg0 += 64; vg1 += 64;                        \
        }                                                                          \
        bf16x8 ak0 = *(const bf16x8*)(&KS[(w * 16 + m16) * 72 + 0 * 32 + quad * 8]); \
        bf16x8 ak1 = *(const bf16x8*)(&KS[(w * 16 + m16) * 72 + 1 * 32 + quad * 8]); \
        bf16x4 va[4];                                                              \
        _Pragma("unroll")                                                          \
        for (int ds = 0; ds < 4; ++ds)                                             \
            va[ds] = *(const bf16x4*)(&VS[(ds * 16 + m16) * 72 + w * 16 + quad * 4]); \
        s16x4 pb[4];                                                               \
        _Pragma("unroll")                                                          \
        for (int n = 0; n < 4; ++n) {                                              \
            f32x4 c = {};                                                          \
            c = __builtin_amdgcn_mfma_f32_16x16x32_bf16(ak0, qf[n][0], c, 0, 0, 0); \
            c = __builtin_amdgcn_mfma_f32_16x16x32_bf16(ak1, qf[n][1], c, 0, 0, 0); \
            bf16x4 pv;                                                             \
            _Pragma("unroll")                                                      \
            for (int r = 0; r < 4; ++r) {                                          \
                const float pp = __builtin_amdgcn_exp2f(c[r]);                     \
                lp[n] += pp;                                                       \
                pv[r] = (bf16_t)pp;                                                \
            }                                                                      \
            pb[n] = as_s16x4(pv);                                                  \
        }                                                                          \
        __builtin_amdgcn_s_setprio(1);                                             \
        _Pragma("unroll")                                                          \
        for (int ds = 0; ds < 4; ++ds)                                             \
            _Pragma("unroll")                                                      \
            for (int n = 0; n < 4; ++n)                                            \
                o[ds][n] = __builtin_amdgcn_mfma_f32_16x16x16bf16_1k(               \
                    as_s16x4(va[ds]), pb[n], o[ds][n], 0, 0, 0);                   \
        __builtin_amdgcn_s_setprio(0);                                             \
        if (tt < 31) {                                                             \
            _Pragma("unroll")                                                      \
            for (int p = 0; p < 2; ++p) {                                          \
                const int row = srow + p * 32;                                     \
                *(bf16x8*)(&KSN[row * 72 + sc8]) = kreg[p];                        \
                *(bf16x8*)(&VSN[row * 72 + sc8]) = vreg[p];                        \
            }                                                                      \
        }                                                                          \
        __syncthreads();                                                           \
    } while (0)

    for (int t = 0; t < 32; t += 2) {
        ATTN_BODY(t,     Ks0, Vt0, Ks1, Vt1);
        ATTN_BODY(t + 1, Ks1, Vt1, Ks0, Vt0);
    }
#undef ATTN_BODY

    // ---- l reduction: over quads (shfl), then over waves (LDS) ----
#pragma unroll
    for (int n = 0; n < 4; ++n) {
        lp[n] += __shfl_xor(lp[n], 16);
        lp[n] += __shfl_xor(lp[n], 32);
    }
    if (quad == 0) {
#pragma unroll
        for (int n = 0; n < 4; ++n) Lred[w * 64 + n * 16 + m16] = lp[n];
    }
    __syncthreads();
    const float linv = 1.0f / (Lred[lane] + Lred[64 + lane] + Lred[128 + lane] + Lred[192 + lane]);

    // ---- O reduction: 4 phases; ALL waves sum+store (wave w owns dims
    // [w*4, w*4+4) of the phase's 16-dim slab; lane = query) ----
    const size_t obase = (size_t)(b * SEQ + q0 + lane) * DIM_ + hh * HDIM;
#pragma unroll
    for (int p = 0; p < 4; ++p) {
        __syncthreads();
#pragma unroll
        for (int n = 0; n < 4; ++n)
#pragma unroll
            for (int r = 0; r < 4; ++r)
                Ored[w * 1040 + (quad * 4 + r) * 65 + n * 16 + m16] = o[p][n][r];
        __syncthreads();
        union { bf16_t e[4]; bf16x4 v; } ob;
#pragma unroll
        for (int d = 0; d < 4; ++d) {
            const int dd = w * 4 + d;
            const float v = Ored[dd * 65 + lane] + Ored[1040 + dd * 65 + lane] +
                            Ored[2080 + dd * 65 + lane] + Ored[3120 + dd * 65 + lane];
            ob.e[d] = (bf16_t)(v * linv);
        }
        *(bf16x4*)(out + obase + p * 16 + w * 4) = ob.v;
    }
}

// ---------------------------------------------------------------------------
extern "C" void kernel_launch(void* const* d_in, const int* in_sizes, int n_in,
                              void* d_out, int out_size, void* d_ws, size_t ws_size,
                              hipStream_t stream) {
    const float* x     = (const float*)d_in[0];
    const float* w_qkv = (const float*)d_in[1];
    const float* w_out = (const float*)d_in[2];
    const float* b_out = (const float*)d_in[3];
    float* out = (float*)d_out;

    const int M = BATCH * SEQ;  // 4096

    bf16_t* qkv_b  = (bf16_t*)d_ws;                            // 4096x3072
    bf16_t* attn_b = qkv_b + (size_t)M * 3 * DIM_;             // 4096x1024
    bf16_t* vt_b   = attn_b + (size_t)M * DIM_;                // 32 heads x 64 x SEQ
    bf16_t* xb     = vt_b + (size_t)BATCH * NHEADS * HDIM * SEQ;
    bf16_t* wqkvb  = xb + (size_t)M * DIM_;
    bf16_t* woutb  = wqkvb + (size_t)3 * DIM_ * DIM_;

    // 0) cast x, w_qkv, w_out to bf16
    cast3<<<(XCNT + WQCNT + WOCNT) / (256 * 8), 256, 0, stream>>>(
        x, w_qkv, w_out, xb, wqkvb, woutb);

    // 1) qkv = x @ w_qkv^T  (q,k -> qkv_b; v -> vt_b transposed)
    gemm_lds<true><<<dim3(3 * DIM_ / 128, M / 128), 256, 0, stream>>>(
        xb, wqkvb, nullptr, qkv_b, vt_b, M, 3 * DIM_, DIM_);

    // 2) RoPE in place on q,k
    rope_bf16<<<(M * 2 * NHEADS) / 256, 256, 0, stream>>>(qkv_b);

    // 3) flash attention -> attn_b
    attn_mfma<<<dim3(SEQ / 64, BATCH * NHEADS), 256, 0, stream>>>(qkv_b, vt_b, attn_b);

    // 4) out = attn @ w_out^T + b_out (fp32), 128x64 tiles -> 512 blocks (2/CU)
    gemm_out64<<<dim3(DIM_ / 64, M / 128), 256, 0, stream>>>(
        attn_b, woutb, b_out, out, M, DIM_, DIM_);
}

// Round 9
// 204.549 us; speedup vs baseline: 1.2267x; 1.0112x over previous
//
#include <hip/hip_runtime.h>
#include <math.h>

typedef __bf16 bf16_t;
typedef bf16_t bf16x8 __attribute__((ext_vector_type(8)));
typedef bf16_t bf16x4 __attribute__((ext_vector_type(4)));
typedef short  s16x4  __attribute__((ext_vector_type(4)));
typedef float  f32x4  __attribute__((ext_vector_type(4)));

#define DIM_   1024
#define NHEADS 16
#define HDIM   64
#define SEQ    2048
#define BATCH  2

// log2(e)/8 : folded into q at RoPE time so attention softmax is exp2(s)
#define QK_SCALE 0.18033688011112042f

__device__ __forceinline__ s16x4 as_s16x4(bf16x4 v) {
    union { bf16x4 b; s16x4 s; } u; u.b = v; return u.s;
}

// async global->LDS, 16 B per lane; LDS dest = wave-uniform base + lane*16
__device__ __forceinline__ void gld16(const bf16_t* g, bf16_t* l) {
    __builtin_amdgcn_global_load_lds(
        (const __attribute__((address_space(1))) void*)g,
        (__attribute__((address_space(3))) void*)l, 16, 0, 0);
}

// ---------------------------------------------------------------------------
// Fused fp32->bf16 cast of x, w_qkv, w_out.
// ---------------------------------------------------------------------------
#define XCNT   (4096u * 1024u)
#define WQCNT  (3072u * 1024u)
#define WOCNT  (1024u * 1024u)
__global__ __launch_bounds__(256) void cast3(const float* __restrict__ s0,
                                             const float* __restrict__ s1,
                                             const float* __restrict__ s2,
                                             bf16_t* __restrict__ d0,
                                             bf16_t* __restrict__ d1,
                                             bf16_t* __restrict__ d2) {
    size_t i = ((size_t)blockIdx.x * 256 + threadIdx.x) * 8;
    const float* s; bf16_t* d; size_t off;
    if (i < XCNT)               { s = s0; d = d0; off = i; }
    else if (i < XCNT + WQCNT)  { s = s1; d = d1; off = i - XCNT; }
    else                        { s = s2; d = d2; off = i - XCNT - WQCNT; }
    float4 a = *(const float4*)(s + off);
    float4 b = *(const float4*)(s + off + 4);
    bf16x8 o = { (bf16_t)a.x, (bf16_t)a.y, (bf16_t)a.z, (bf16_t)a.w,
                 (bf16_t)b.x, (bf16_t)b.y, (bf16_t)b.z, (bf16_t)b.w };
    *(bf16x8*)(d + off) = o;
}

// ---------------------------------------------------------------------------
// bf16 GEMM, 128x128 tile, BK=32, LDS double-buffer 2-phase (R8).
// ---------------------------------------------------------------------------
template <bool QKV>
__global__ __launch_bounds__(256) void gemm_lds(const bf16_t* __restrict__ A,
                                                const bf16_t* __restrict__ B,
                                                const float* __restrict__ bias,
                                                void* __restrict__ Cout,
                                                bf16_t* __restrict__ vt,
                                                int M, int N, int K) {
    __shared__ __align__(16) bf16_t As[2][128 * 32];
    __shared__ __align__(16) bf16_t Bs[2][128 * 32];
    const int tid  = threadIdx.x;
    const int m0   = blockIdx.y * 128;
    const int n0   = blockIdx.x * 128;
    const int w    = tid >> 6;
    const int lane = tid & 63;
    const int m16  = lane & 15;
    const int quad = lane >> 4;
    const int wm   = (w >> 1) * 64;
    const int wn   = (w & 1) * 64;
    const int lrow = lane >> 2;
    const int lcol = (lane & 3) * 8;

    const bf16_t* pa0 = A + (size_t)(m0 + w * 16 + lrow) * K + lcol;
    const bf16_t* pb0 = B + (size_t)(n0 + w * 16 + lrow) * K + lcol;
    const int sOffA0 = (w * 16) * 32;
    const int sOffA1 = (64 + w * 16) * 32;

    // prologue: stage k=0 into buffer 0
    gld16(pa0, (bf16_t*)As + sOffA0);
    gld16(pa0 + (size_t)64 * K, (bf16_t*)As + sOffA1);
    gld16(pb0, (bf16_t*)Bs + sOffA0);
    gld16(pb0 + (size_t)64 * K, (bf16_t*)Bs + sOffA1);
    __syncthreads();

    f32x4 acc[4][4] = {};
    int buf = 0;

    for (int k0 = 0; k0 < K; k0 += 32) {
        const int nb = buf ^ 1;
        if (k0 + 32 < K) {  // stage next tile into the other buffer
            gld16(pa0 + k0 + 32, (bf16_t*)As + nb * 4096 + sOffA0);
            gld16(pa0 + (size_t)64 * K + k0 + 32, (bf16_t*)As + nb * 4096 + sOffA1);
            gld16(pb0 + k0 + 32, (bf16_t*)Bs + nb * 4096 + sOffA0);
            gld16(pb0 + (size_t)64 * K + k0 + 32, (bf16_t*)Bs + nb * 4096 + sOffA1);
        }
        const bf16_t* sA = (const bf16_t*)As + buf * 4096;
        const bf16_t* sB = (const bf16_t*)Bs + buf * 4096;
        bf16x8 af[4], bfr[4];
#pragma unroll
        for (int i = 0; i < 4; ++i)
            af[i] = *(const bf16x8*)(sA + (wm + i * 16 + m16) * 32 + quad * 8);
#pragma unroll
        for (int j = 0; j < 4; ++j)
            bfr[j] = *(const bf16x8*)(sB + (wn + j * 16 + m16) * 32 + quad * 8);
#pragma unroll
        for (int i = 0; i < 4; ++i)
#pragma unroll
            for (int j = 0; j < 4; ++j)
                acc[i][j] = __builtin_amdgcn_mfma_f32_16x16x32_bf16(af[i], bfr[j], acc[i][j], 0, 0, 0);
        __syncthreads();   // vmcnt(0) drain lands here, AFTER compute
        buf = nb;
    }

    if (QKV && n0 >= 2 * DIM_) {
        const int b      = m0 >> 11;
        const int s_base = (m0 & (SEQ - 1)) + wm;
#pragma unroll
        for (int j = 0; j < 4; ++j) {
            const int cit = wn + j * 16 + m16;
            const int h   = ((n0 - 2 * DIM_) >> 6) + (cit >> 6);
            const int d   = cit & 63;
            bf16_t* vrow = vt + ((size_t)(b * 16 + h) * 64 + d) * SEQ + s_base;
#pragma unroll
            for (int i = 0; i < 4; ++i) {
                bf16x4 ov = { (bf16_t)acc[i][j][0], (bf16_t)acc[i][j][1],
                              (bf16_t)acc[i][j][2], (bf16_t)acc[i][j][3] };
                *(bf16x4*)(vrow + i * 16 + quad * 4) = ov;
            }
        }
    } else if (QKV) {
        bf16_t* C = (bf16_t*)Cout;
#pragma unroll
        for (int i = 0; i < 4; ++i)
#pragma unroll
            for (int j = 0; j < 4; ++j) {
                const int col = n0 + wn + j * 16 + m16;
#pragma unroll
                for (int r = 0; r < 4; ++r)
                    C[(size_t)(m0 + wm + i * 16 + quad * 4 + r) * N + col] = (bf16_t)acc[i][j][r];
            }
    } else {
        float* C = (float*)Cout;
#pragma unroll
        for (int j = 0; j < 4; ++j) {
            const int col = n0 + wn + j * 16 + m16;
            const float bv = bias[col];
#pragma unroll
            for (int i = 0; i < 4; ++i)
#pragma unroll
                for (int r = 0; r < 4; ++r)
                    C[(size_t)(m0 + wm + i * 16 + quad * 4 + r) * N + col] = acc[i][j][r] + bv;
        }
    }
}

// ---------------------------------------------------------------------------
// Output GEMM, 128x64 tile, LDS double-buffer 2-phase (R8).
// ---------------------------------------------------------------------------
__global__ __launch_bounds__(256) void gemm_out64(const bf16_t* __restrict__ A,
                                                  const bf16_t* __restrict__ B,
                                                  const float* __restrict__ bias,
                                                  float* __restrict__ C,
                                                  int M, int N, int K) {
    __shared__ __align__(16) bf16_t As[2][128 * 32];
    __shared__ __align__(16) bf16_t Bs[2][64 * 32];
    const int tid  = threadIdx.x;
    const int m0   = blockIdx.y * 128;
    const int n0   = blockIdx.x * 64;
    const int w    = tid >> 6;
    const int lane = tid & 63;
    const int m16  = lane & 15;
    const int quad = lane >> 4;
    const int wm   = (w >> 1) * 64;
    const int wn   = (w & 1) * 32;
    const int lrow = lane >> 2;
    const int lcol = (lane & 3) * 8;

    const bf16_t* pa0 = A + (size_t)(m0 + w * 16 + lrow) * K + lcol;
    const bf16_t* pb0 = B + (size_t)(n0 + w * 16 + lrow) * K + lcol;
    const int sOff0 = (w * 16) * 32;
    const int sOff1 = (64 + w * 16) * 32;

    // prologue: stage k=0 into buffer 0
    gld16(pa0, (bf16_t*)As + sOff0);
    gld16(pa0 + (size_t)64 * K, (bf16_t*)As + sOff1);
    gld16(pb0, (bf16_t*)Bs + sOff0);
    __syncthreads();

    f32x4 acc[4][2] = {};
    int buf = 0;

    for (int k0 = 0; k0 < K; k0 += 32) {
        const int nb = buf ^ 1;
        if (k0 + 32 < K) {
            gld16(pa0 + k0 + 32, (bf16_t*)As + nb * 4096 + sOff0);
            gld16(pa0 + (size_t)64 * K + k0 + 32, (bf16_t*)As + nb * 4096 + sOff1);
            gld16(pb0 + k0 + 32, (bf16_t*)Bs + nb * 2048 + sOff0);
        }
        const bf16_t* sA = (const bf16_t*)As + buf * 4096;
        const bf16_t* sB = (const bf16_t*)Bs + buf * 2048;
        bf16x8 af[4], bfr[2];
#pragma unroll
        for (int i = 0; i < 4; ++i)
            af[i] = *(const bf16x8*)(sA + (wm + i * 16 + m16) * 32 + quad * 8);
#pragma unroll
        for (int j = 0; j < 2; ++j)
            bfr[j] = *(const bf16x8*)(sB + (wn + j * 16 + m16) * 32 + quad * 8);
#pragma unroll
        for (int i = 0; i < 4; ++i)
#pragma unroll
            for (int j = 0; j < 2; ++j)
                acc[i][j] = __builtin_amdgcn_mfma_f32_16x16x32_bf16(af[i], bfr[j], acc[i][j], 0, 0, 0);
        __syncthreads();
        buf = nb;
    }

#pragma unroll
    for (int j = 0; j < 2; ++j) {
        const int col = n0 + wn + j * 16 + m16;
        const float bv = bias[col];
#pragma unroll
        for (int i = 0; i < 4; ++i)
#pragma unroll
            for (int r = 0; r < 4; ++r)
                C[(size_t)(m0 + wm + i * 16 + quad * 4 + r) * N + col] = acc[i][j][r] + bv;
    }
}

// ---------------------------------------------------------------------------
// RoPE in place on bf16 qkv (q and k thirds). q scaled by QK_SCALE.
// ---------------------------------------------------------------------------
__global__ __launch_bounds__(256) void rope_bf16(bf16_t* __restrict__ qkv) {
    __shared__ float ctab[8][32];
    __shared__ float stab[8][32];
    const int tid = threadIdx.x;
    const int sl  = tid >> 5, j = tid & 31;
    const int s   = (int)((blockIdx.x * 8 + sl) & (SEQ - 1));
    const float freq = exp2f(-0.41524101186092029f * (float)j);  // 10000^(-j/32)
    float sn, cs;
    sincosf((float)s * freq, &sn, &cs);
    ctab[sl][j] = cs;
    stab[sl][j] = sn;
    __syncthreads();

    const int gid   = blockIdx.x * 256 + tid;
    const int m     = gid >> 5;
    const int rr    = gid & 31;
    const int which = rr >> 4;
    const int hh    = rr & 15;
    const float osc = (which == 0) ? QK_SCALE : 1.0f;

    bf16_t* p = qkv + (size_t)m * (3 * DIM_) + which * DIM_ + hh * HDIM;
    union { bf16_t e[64]; bf16x8 v[8]; } X, O;
#pragma unroll
    for (int i = 0; i < 8; ++i) X.v[i] = *(const bf16x8*)(p + i * 8);
#pragma unroll
    for (int t = 0; t < 32; ++t) {
        const float x1 = (float)X.e[2 * t];
        const float x2 = (float)X.e[2 * t + 1];
        const float c  = ctab[sl][t];
        const float s2 = stab[sl][t];
        O.e[t]      = (bf16_t)((x1 * c - x2 * s2) * osc);
        O.e[32 + t] = (bf16_t)((x1 * s2 + x2 * c) * osc);
    }
#pragma unroll
    for (int i = 0; i < 8; ++i) *(bf16x8*)(p + i * 8) = O.v[i];
}

// ---------------------------------------------------------------------------
// Flash attention, key-split waves. R9: T15 double-pipeline — PV(t-1) issues
// during tile t's QK/exp2 phase (PV depends only on previous tile's regs, so
// the MFMA pipe fills while the softmax VALU burst runs). Named ping-pong
// register sets pbA/vaA, pbB/vaB (no runtime indexing). Structure otherwise
// R7/R8: LDS dbuf, one barrier/tile, pointer-increment staging, parallel
// epilogue.
// ---------------------------------------------------------------------------
__global__ __launch_bounds__(256) void attn_mfma(const bf16_t* __restrict__ qkv,
                                                 const bf16_t* __restrict__ vt,
                                                 bf16_t* __restrict__ out) {
    __shared__ __align__(16) char smem[37888];
    bf16_t* Ks0  = (bf16_t*)smem;              // 64 x 72 bf16 (9216 B)
    bf16_t* Vt0  = (bf16_t*)(smem + 9216);
    bf16_t* Ks1  = (bf16_t*)(smem + 18432);
    bf16_t* Vt1  = (bf16_t*)(smem + 27648);
    float*  Ored = (float*)smem;               // epilogue alias: 16640 B
    float*  Lred = (float*)(smem + 36864);     // 1024 B

    const int tid  = threadIdx.x;
    const int w    = tid >> 6;
    const int lane = tid & 63;
    const int m16  = lane & 15;
    const int quad = lane >> 4;
    const int bh   = blockIdx.y;
    const int b    = bh >> 4;
    const int hh   = bh & 15;
    const int q0   = blockIdx.x * 64;

    const size_t rs = 3 * DIM_;
    const bf16_t* qbase = qkv + (size_t)(b * SEQ) * rs + hh * HDIM;
    const bf16_t* kbase = qbase + DIM_;
    const bf16_t* vtg   = vt + (size_t)bh * 64 * SEQ;

    // Q fragments: qf[n][kt] = Q[q0+n*16+m16][kt*32+quad*8 ..+7]
    bf16x8 qf[4][2];
#pragma unroll
    for (int n = 0; n < 4; ++n)
#pragma unroll
        for (int kt = 0; kt < 2; ++kt)
            qf[n][kt] = *(const bf16x8*)(qbase + (size_t)(q0 + n * 16 + m16) * rs + kt * 32 + quad * 8);

    f32x4 o[4][4] = {};  // o[ds][n]: partial O^T over this wave's keys
    float lp[4] = {};    // per-lane partial l for q = n*16+m16

    // coalesced staging geometry: 256 threads cover 32 rows/pass
    const int srow = tid >> 3;          // 0..31
    const int sc8  = (tid & 7) * 8;     // 0..56

    bf16x8 kreg[2], vreg[2];

    // prologue: tile 0 -> regs -> buf0 -> barrier
#pragma unroll
    for (int p = 0; p < 2; ++p) {
        const int row = srow + p * 32;
        kreg[p] = *(const bf16x8*)(kbase + (size_t)row * rs + sc8);
        vreg[p] = *(const bf16x8*)(vtg + (size_t)row * SEQ + sc8);
    }
#pragma unroll
    for (int p = 0; p < 2; ++p) {
        const int row = srow + p * 32;
        *(bf16x8*)(&Ks0[row * 72 + sc8]) = kreg[p];
        *(bf16x8*)(&Vt0[row * 72 + sc8]) = vreg[p];
    }
    __syncthreads();

    // persistent prefetch pointers (tile 1 rows), advanced by one tile/body
    const bf16_t* kg0 = kbase + (size_t)(64 + srow) * rs + sc8;
    const bf16_t* kg1 = kg0 + (size_t)32 * rs;
    const bf16_t* vg0 = vtg + (size_t)srow * SEQ + 64 + sc8;
    const bf16_t* vg1 = vg0 + (size_t)32 * SEQ;
    const size_t kadv = (size_t)64 * rs;

    s16x4  pbA[4], pbB[4];   // P (exp2 scores) ping-pong
    bf16x4 vaA[4], vaB[4];   // V^T fragments ping-pong

    // ---- warmup: tile 0 QK/exp2 -> pbA/vaA; stage tile 1 -> buf1 (no PV) --
    {
        kreg[0] = *(const bf16x8*)(kg0);
        kreg[1] = *(const bf16x8*)(kg1);
        vreg[0] = *(const bf16x8*)(vg0);
        vreg[1] = *(const bf16x8*)(vg1);
        kg0 += kadv; kg1 += kadv; vg0 += 64; vg1 += 64;

        bf16x8 ak0 = *(const bf16x8*)(&Ks0[(w * 16 + m16) * 72 + 0 * 32 + quad * 8]);
        bf16x8 ak1 = *(const bf16x8*)(&Ks0[(w * 16 + m16) * 72 + 1 * 32 + quad * 8]);
#pragma unroll
        for (int ds = 0; ds < 4; ++ds)
            vaA[ds] = *(const bf16x4*)(&Vt0[(ds * 16 + m16) * 72 + w * 16 + quad * 4]);
#pragma unroll
        for (int n = 0; n < 4; ++n) {
            f32x4 c = {};
            c = __builtin_amdgcn_mfma_f32_16x16x32_bf16(ak0, qf[n][0], c, 0, 0, 0);
            c = __builtin_amdgcn_mfma_f32_16x16x32_bf16(ak1, qf[n][1], c, 0, 0, 0);
            bf16x4 pv;
#pragma unroll
            for (int r = 0; r < 4; ++r) {
                const float pp = __builtin_amdgcn_exp2f(c[r]);
                lp[n] += pp;
                pv[r] = (bf16_t)pp;
            }
            pbA[n] = as_s16x4(pv);
        }
#pragma unroll
        for (int p = 0; p < 2; ++p) {
            const int row = srow + p * 32;
            *(bf16x8*)(&Ks1[row * 72 + sc8]) = kreg[p];
            *(bf16x8*)(&Vt1[row * 72 + sc8]) = vreg[p];
        }
        __syncthreads();
    }

    // body(T): prefetch T+1 regs; QK/exp2(T) -> PBc/VAc; PV(T-1) with PBp/VAp;
    // write T+1 -> KSN/VSN; barrier.
#define ATTN_BODY(T, KS, VS, KSN, VSN, PBc, VAc, PBp, VAp)                         \
    do {                                                                           \
        const int tt = (T);                                                        \
        if (tt < 31) {                                                             \
            kreg[0] = *(const bf16x8*)(kg0);                                       \
            kreg[1] = *(const bf16x8*)(kg1);                                       \
            vreg[0] = *(const bf16x8*)(vg0);                                       \
            vreg[1] = *(const bf16x8*)(vg1);                                       \
            kg0 += kadv; kg1 += kadv; vg0 += 64; vg1 += 64;                        \
        }                                                                          \
        bf16x8 ak0 = *(const bf16x8*)(&KS[(w * 16 + m16) * 72 + 0 * 32 + quad * 8]); \
        bf16x8 ak1 = *(const bf16x8*)(&KS[(w * 16 + m16) * 72 + 1 * 32 + quad * 8]); \
        _Pragma("unroll")                                                          \
        for (int ds = 0; ds < 4; ++ds)                                             \
            VAc[ds] = *(const bf16x4*)(&VS[(ds * 16 + m16) * 72 + w * 16 + quad * 4]); \
        _Pragma("unroll")                                                          \
        for (int n = 0; n < 4; ++n) {                                              \
            f32x4 c = {};                                                          \
            c = __builtin_amdgcn_mfma_f32_16x16x32_bf16(ak0, qf[n][0], c, 0, 0, 0); \
            c = __builtin_amdgcn_mfma_f32_16x16x32_bf16(ak1, qf[n][1], c, 0, 0, 0); \
            bf16x4 pv;                                                             \
            _Pragma("unroll")                                                      \
            for (int r = 0; r < 4; ++r) {                                          \
                const float pp = __builtin_amdgcn_exp2f(c[r]);                     \
                lp[n] += pp;                                                       \
                pv[r] = (bf16_t)pp;                                                \
            }                                                                      \
            PBc[n] = as_s16x4(pv);                                                 \
        }                                                                          \
        __builtin_amdgcn_s_setprio(1);                                             \
        _Pragma("unroll")                                                          \
        for (int ds = 0; ds < 4; ++ds)                                             \
            _Pragma("unroll")                                                      \
            for (int n = 0; n < 4; ++n)                                            \
                o[ds][n] = __builtin_amdgcn_mfma_f32_16x16x16bf16_1k(               \
                    as_s16x4(VAp[ds]), PBp[n], o[ds][n], 0, 0, 0);                 \
        __builtin_amdgcn_s_setprio(0);                                             \
        if (tt < 31) {                                                             \
            _Pragma("unroll")                                                      \
            for (int p = 0; p < 2; ++p) {                                          \
                const int row = srow + p * 32;                                     \
                *(bf16x8*)(&KSN[row * 72 + sc8]) = kreg[p];                        \
                *(bf16x8*)(&VSN[row * 72 + sc8]) = vreg[p];                        \
            }                                                                      \
        }                                                                          \
        __syncthreads();                                                           \
    } while (0)

    for (int t = 1; t < 31; t += 2) {
        ATTN_BODY(t,     Ks1, Vt1, Ks0, Vt0, pbB, vaB, pbA, vaA);
        ATTN_BODY(t + 1, Ks0, Vt0, Ks1, Vt1, pbA, vaA, pbB, vaB);
    }
    ATTN_BODY(31, Ks1, Vt1, Ks0, Vt0, pbB, vaB, pbA, vaA);
#undef ATTN_BODY

    // final PV for tile 31
    __builtin_amdgcn_s_setprio(1);
#pragma unroll
    for (int ds = 0; ds < 4; ++ds)
#pragma unroll
        for (int n = 0; n < 4; ++n)
            o[ds][n] = __builtin_amdgcn_mfma_f32_16x16x16bf16_1k(
                as_s16x4(vaB[ds]), pbB[n], o[ds][n], 0, 0, 0);
    __builtin_amdgcn_s_setprio(0);

    // ---- l reduction: over quads (shfl), then over waves (LDS) ----
#pragma unroll
    for (int n = 0; n < 4; ++n) {
        lp[n] += __shfl_xor(lp[n], 16);
        lp[n] += __shfl_xor(lp[n], 32);
    }
    if (quad == 0) {
#pragma unroll
        for (int n = 0; n < 4; ++n) Lred[w * 64 + n * 16 + m16] = lp[n];
    }
    __syncthreads();
    const float linv = 1.0f / (Lred[lane] + Lred[64 + lane] + Lred[128 + lane] + Lred[192 + lane]);

    // ---- O reduction: 4 phases; ALL waves sum+store (wave w owns dims
    // [w*4, w*4+4) of the phase's 16-dim slab; lane = query) ----
    const size_t obase = (size_t)(b * SEQ + q0 + lane) * DIM_ + hh * HDIM;
#pragma unroll
    for (int p = 0; p < 4; ++p) {
        __syncthreads();
#pragma unroll
        for (int n = 0; n < 4; ++n)
#pragma unroll
            for (int r = 0; r < 4; ++r)
                Ored[w * 1040 + (quad * 4 + r) * 65 + n * 16 + m16] = o[p][n][r];
        __syncthreads();
        union { bf16_t e[4]; bf16x4 v; } ob;
#pragma unroll
        for (int d = 0; d < 4; ++d) {
            const int dd = w * 4 + d;
            const float v = Ored[dd * 65 + lane] + Ored[1040 + dd * 65 + lane] +
                            Ored[2080 + dd * 65 + lane] + Ored[3120 + dd * 65 + lane];
            ob.e[d] = (bf16_t)(v * linv);
        }
        *(bf16x4*)(out + obase + p * 16 + w * 4) = ob.v;
    }
}

// ---------------------------------------------------------------------------
extern "C" void kernel_launch(void* const* d_in, const int* in_sizes, int n_in,
                              void* d_out, int out_size, void* d_ws, size_t ws_size,
                              hipStream_t stream) {
    const float* x     = (const float*)d_in[0];
    const float* w_qkv = (const float*)d_in[1];
    const float* w_out = (const float*)d_in[2];
    const float* b_out = (const float*)d_in[3];
    float* out = (float*)d_out;

    const int M = BATCH * SEQ;  // 4096

    bf16_t* qkv_b  = (bf16_t*)d_ws;                            // 4096x3072
    bf16_t* attn_b = qkv_b + (size_t)M * 3 * DIM_;             // 4096x1024
    bf16_t* vt_b   = attn_b + (size_t)M * DIM_;                // 32 heads x 64 x SEQ
    bf16_t* xb     = vt_b + (size_t)BATCH * NHEADS * HDIM * SEQ;
    bf16_t* wqkvb  = xb + (size_t)M * DIM_;
    bf16_t* woutb  = wqkvb + (size_t)3 * DIM_ * DIM_;

    // 0) cast x, w_qkv, w_out to bf16
    cast3<<<(XCNT + WQCNT + WOCNT) / (256 * 8), 256, 0, stream>>>(
        x, w_qkv, w_out, xb, wqkvb, woutb);

    // 1) qkv = x @ w_qkv^T  (q,k -> qkv_b; v -> vt_b transposed)
    gemm_lds<true><<<dim3(3 * DIM_ / 128, M / 128), 256, 0, stream>>>(
        xb, wqkvb, nullptr, qkv_b, vt_b, M, 3 * DIM_, DIM_);

    // 2) RoPE in place on q,k
    rope_bf16<<<(M * 2 * NHEADS) / 256, 256, 0, stream>>>(qkv_b);

    // 3) flash attention -> attn_b
    attn_mfma<<<dim3(SEQ / 64, BATCH * NHEADS), 256, 0, stream>>>(qkv_b, vt_b, attn_b);

    // 4) out = attn @ w_out^T + b_out (fp32), 128x64 tiles -> 512 blocks (2/CU)
    gemm_out64<<<dim3(DIM_ / 64, M / 128), 256, 0, stream>>>(
        attn_b, woutb, b_out, out, M, DIM_, DIM_);
}